// Round 13
// baseline (520.388 us; speedup 1.0000x reference)
//
#include <hip/hip_runtime.h>
#include <hip/hip_bf16.h>

#define DD 128

typedef __attribute__((ext_vector_type(8))) short short8;
typedef __attribute__((ext_vector_type(4))) float f32x4;
typedef __attribute__((ext_vector_type(2))) float f32x2;

static __device__ __forceinline__ int gtid() {
    return blockIdx.x * blockDim.x + threadIdx.x;
}

static __device__ __forceinline__ ushort f2bfu(float f) {
    __hip_bfloat16 h = __float2bfloat16(f);
    return *reinterpret_cast<ushort*>(&h);
}

// ---- fp8 e4m3fn encode/decode (manual fallback, RNE, subnormal-correct) ----
static __device__ __forceinline__ unsigned int fp8e(float f) {
    unsigned int s = (__float_as_uint(f) >> 31) << 7;
    float a = fabsf(f);
    if (a < 0.015625f) return s | (unsigned int)rintf(a * 512.0f);
    unsigned int u = __float_as_uint(a);
    u += 0x0007FFFFu + ((u >> 20) & 1u);
    unsigned int e8 = (u >> 23) - 120u;
    unsigned int m = (u >> 20) & 7u;
    if (e8 > 15u || (e8 == 15u && m == 7u)) return s | 0x7Eu;
    return s | (e8 << 3) | m;
}

static __device__ __forceinline__ float fp8d(unsigned int b) {
    unsigned int t = b & 0x7Fu;
    float v = (t >= 8u) ? __uint_as_float((t << 20) + 0x3C000000u)
                        : (float)t * 0.001953125f;
    return (b & 0x80u) ? -v : v;
}

static __device__ __forceinline__ unsigned int pk8x2(float a, float b) {
#if __has_builtin(__builtin_amdgcn_cvt_pk_fp8_f32)
    return (unsigned int)__builtin_amdgcn_cvt_pk_fp8_f32(a, b, 0, false);
#else
    return fp8e(a) | (fp8e(b) << 8);
#endif
}

static __device__ __forceinline__ void fp8x4_dec(unsigned int u, float* f) {
#if __has_builtin(__builtin_amdgcn_cvt_pk_f32_fp8)
    f32x2 lo = __builtin_amdgcn_cvt_pk_f32_fp8((int)u, false);
    f32x2 hi = __builtin_amdgcn_cvt_pk_f32_fp8((int)u, true);
    f[0] = lo[0]; f[1] = lo[1]; f[2] = hi[0]; f[3] = hi[1];
#else
    f[0] = fp8d(u & 0xFFu);
    f[1] = fp8d((u >> 8) & 0xFFu);
    f[2] = fp8d((u >> 16) & 0xFFu);
    f[3] = fp8d((u >> 24) & 0xFFu);
#endif
}

// ---------- binned CSR build (counting sort by dst) ----------
// bins of 64 rows: bin = dst >> 6

__global__ void bincount_kernel(const int* __restrict__ dst, int* __restrict__ binCounts, int e) {
    int i = gtid();
    if (i < e) atomicAdd(&binCounts[dst[i] >> 6], 1);
}

// single block, 1024 threads: exclusive scan of bin counts (m <= 1024)
__global__ __launch_bounds__(1024) void binscan_kernel(
    const int* __restrict__ binCounts, int* __restrict__ binptr, int* __restrict__ binCur,
    int* __restrict__ rowptr, int m, int e, int n) {
    __shared__ int s[1024];
    int tid = threadIdx.x;
    int v = (tid < m) ? binCounts[tid] : 0;
    s[tid] = v;
    __syncthreads();
    for (int off = 1; off < 1024; off <<= 1) {
        int t = (tid >= off) ? s[tid - off] : 0;
        __syncthreads();
        s[tid] += t;
        __syncthreads();
    }
    if (tid < m) {
        int ex = s[tid] - v;
        binptr[tid] = ex;
        binCur[tid] = ex;
    }
    if (tid == 0) {
        binptr[m] = e;
        rowptr[n] = e;
    }
}

// scatter packed (src,dst) into per-bin contiguous windows
__global__ void binfill_kernel(const int* __restrict__ ei, int* __restrict__ binCur,
                               uint2* __restrict__ binEdges, int e) {
    int i = gtid();
    if (i >= e) return;
    int s = ei[i];
    int d = ei[e + i];
    int pos = atomicAdd(&binCur[d >> 6], 1);
    uint2 ed;
    ed.x = (unsigned int)s;
    ed.y = (unsigned int)d;
    binEdges[pos] = ed;
}

// one block per bin: per-row counts in LDS -> wave scan -> rowptr + in-bin scatter
__global__ __launch_bounds__(256) void csr_from_bins_kernel(
    const uint2* __restrict__ binEdges, const int* __restrict__ binptr,
    int* __restrict__ rowptr, int* __restrict__ csr_src, int n) {
    __shared__ int cnts[64];
    __shared__ int curs[64];
    int b = blockIdx.x;
    int row0 = b << 6;
    int base = binptr[b];
    int cnt = binptr[b + 1] - base;
    int tid = threadIdx.x;
    if (tid < 64) cnts[tid] = 0;
    __syncthreads();
    for (int i = tid; i < cnt; i += 256) {
        uint2 ed = binEdges[base + i];
        atomicAdd(&cnts[ed.y - row0], 1);
    }
    __syncthreads();
    if (tid < 64) {
        int v = cnts[tid];
        int inc = v;
#pragma unroll
        for (int off = 1; off < 64; off <<= 1) {
            int t = __shfl_up(inc, off);
            if (tid >= off) inc += t;
        }
        int ex = inc - v;
        if (row0 + tid < n) rowptr[row0 + tid] = base + ex;
        curs[tid] = ex;
    }
    __syncthreads();
    for (int i = tid; i < cnt; i += 256) {
        uint2 ed = binEdges[base + i];
        int pos = base + atomicAdd(&curs[ed.y - row0], 1);
        csr_src[pos] = (int)ed.x;
    }
}

__global__ void dinv_kernel(float* __restrict__ dinv, const int* __restrict__ rowptr, int n) {
    int i = gtid();
    if (i < n) dinv[i] = rsqrtf(1.0f + (float)(rowptr[i + 1] - rowptr[i]));
}

// ---------- x -> bf16 ----------
__global__ void cvt_kernel(const float* __restrict__ x, __hip_bfloat16* __restrict__ xh, size_t m) {
    size_t i = (size_t)blockIdx.x * blockDim.x + threadIdx.x;
    if (i < m) xh[i] = __float2bfloat16(x[i]);
}

// ---------- W -> bf16 MFMA B-fragment order ----------
__global__ __launch_bounds__(256) void wpack_kernel(const float* __restrict__ gcn_w,
                                                    ushort* __restrict__ wfrag) {
    int tid = blockIdx.x * 256 + threadIdx.x;
    if (tid >= 3 * 4 * 8 * 64) return;
    int lane = tid & 63;
    int c = (tid >> 6) & 7;
    int s = (tid >> 9) & 3;
    int l = tid >> 11;
    const float* W = gcn_w + (size_t)l * 128 * 128;
    int col = c * 16 + (lane & 15);
    int k0 = s * 32 + (lane >> 4) * 8;
    ushort u[8];
#pragma unroll
    for (int j = 0; j < 8; ++j) {
        u[j] = f2bfu(W[(size_t)(k0 + j) * 128 + col]);
    }
    *reinterpret_cast<uint4*>(wfrag + (size_t)tid * 8) = *reinterpret_cast<const uint4*>(u);
}

// ---------- aggregate-first (no bias/relu): aggh = Ah ----------

// layer-0: bf16 source [n][128]
__global__ __launch_bounds__(256) void aggregate_bf16_kernel(
    const ushort* __restrict__ src, const int* __restrict__ rowptr,
    const int* __restrict__ csr_src, const float* __restrict__ dinv,
    ushort* __restrict__ aggh, int n) {
    int gid = gtid();
    int row = gid >> 6;
    if (row >= n) return;
    int lane = threadIdx.x & 63;
    int g = lane >> 4;
    int c = lane & 15;
    int j0 = rowptr[row], j1 = rowptr[row + 1];
    float dr = dinv[row];
    float acc[8] = {0.f, 0.f, 0.f, 0.f, 0.f, 0.f, 0.f, 0.f};
    for (int j = j0 + g; j < j1; j += 4) {
        int s = csr_src[j];
        float cf = dinv[s] * dr;
        uint4 v = *reinterpret_cast<const uint4*>(src + (size_t)s * 128 + c * 8);
        const unsigned int* u = (const unsigned int*)&v;
#pragma unroll
        for (int q = 0; q < 4; ++q) {
            acc[2 * q] = fmaf(cf, __uint_as_float(u[q] << 16), acc[2 * q]);
            acc[2 * q + 1] = fmaf(cf, __uint_as_float(u[q] & 0xffff0000u), acc[2 * q + 1]);
        }
    }
#pragma unroll
    for (int k = 0; k < 8; ++k) {
        acc[k] += __shfl_xor(acc[k], 16);
        acc[k] += __shfl_xor(acc[k], 32);
    }
    float d2 = dr * dr;
    uint4 sv = *reinterpret_cast<const uint4*>(src + (size_t)row * 128 + c * 8);
    const unsigned int* su = (const unsigned int*)&sv;
#pragma unroll
    for (int q = 0; q < 4; ++q) {
        acc[2 * q] = fmaf(d2, __uint_as_float(su[q] << 16), acc[2 * q]);
        acc[2 * q + 1] = fmaf(d2, __uint_as_float(su[q] & 0xffff0000u), acc[2 * q + 1]);
    }
    if (g == 0) {
        unsigned int pk[4];
#pragma unroll
        for (int q = 0; q < 4; ++q) {
            pk[q] = (unsigned int)f2bfu(acc[2 * q]) | ((unsigned int)f2bfu(acc[2 * q + 1]) << 16);
        }
        *reinterpret_cast<uint4*>(aggh + (size_t)row * 128 + c * 8) =
            *reinterpret_cast<const uint4*>(pk);
    }
}

// layer>=1: fp8 source slice of zq (row stride 384)
__global__ __launch_bounds__(256) void aggregate_fp8_kernel(
    const unsigned char* __restrict__ srcq, const int* __restrict__ rowptr,
    const int* __restrict__ csr_src, const float* __restrict__ dinv,
    ushort* __restrict__ aggh, int n) {
    int gid = gtid();
    int row = gid >> 6;
    if (row >= n) return;
    int lane = threadIdx.x & 63;
    int g = lane >> 4;
    int c = lane & 15;
    int j0 = rowptr[row], j1 = rowptr[row + 1];
    float dr = dinv[row];
    float acc[8] = {0.f, 0.f, 0.f, 0.f, 0.f, 0.f, 0.f, 0.f};
    for (int j = j0 + g; j < j1; j += 4) {
        int s = csr_src[j];
        float cf = dinv[s] * dr;
        uint2 v = *reinterpret_cast<const uint2*>(srcq + (size_t)s * 384 + c * 8);
        float f[8];
        fp8x4_dec(v.x, f);
        fp8x4_dec(v.y, f + 4);
#pragma unroll
        for (int k = 0; k < 8; ++k) acc[k] = fmaf(cf, f[k], acc[k]);
    }
#pragma unroll
    for (int k = 0; k < 8; ++k) {
        acc[k] += __shfl_xor(acc[k], 16);
        acc[k] += __shfl_xor(acc[k], 32);
    }
    float d2 = dr * dr;
    uint2 sv = *reinterpret_cast<const uint2*>(srcq + (size_t)row * 384 + c * 8);
    float sf[8];
    fp8x4_dec(sv.x, sf);
    fp8x4_dec(sv.y, sf + 4);
#pragma unroll
    for (int k = 0; k < 8; ++k) acc[k] = fmaf(d2, sf[k], acc[k]);
    if (g == 0) {
        unsigned int pk[4];
#pragma unroll
        for (int q = 0; q < 4; ++q) {
            pk[q] = (unsigned int)f2bfu(acc[2 * q]) | ((unsigned int)f2bfu(acc[2 * q + 1]) << 16);
        }
        *reinterpret_cast<uint4*>(aggh + (size_t)row * 128 + c * 8) =
            *reinterpret_cast<const uint4*>(pk);
    }
}

// ---------- MFMA GEMM: aggh @ W + bias -> relu -> zq (fp8) + zqw (fp8*pw*8) ----------
__global__ __launch_bounds__(256) void gemm_mfma_kernel(
    const ushort* __restrict__ aggh, const ushort* __restrict__ wfrag,
    const float* __restrict__ bias, const float* __restrict__ pwsl,
    unsigned char* __restrict__ zq_sl, unsigned char* __restrict__ zqw_sl, int ntiles) {
    int lane = threadIdx.x & 63;
    int wv = threadIdx.x >> 6;
    short8 b0[4], b1[4];
    int c0 = wv * 2;
#pragma unroll
    for (int s = 0; s < 4; ++s) {
        b0[s] = *reinterpret_cast<const short8*>(wfrag + ((size_t)(s * 8 + c0) * 64 + lane) * 8);
        b1[s] = *reinterpret_cast<const short8*>(wfrag + ((size_t)(s * 8 + c0 + 1) * 64 + lane) * 8);
    }
    int rlo = lane & 15;
    int kg = lane >> 4;
    int col0 = wv * 32 + rlo;
    int col1 = col0 + 16;
    float bias0 = bias[col0], bias1 = bias[col1];
    float pw0 = pwsl[col0] * 8.0f, pw1 = pwsl[col1] * 8.0f;
    for (int rt = blockIdx.x; rt < ntiles; rt += gridDim.x) {
        const ushort* ap = aggh + (size_t)(rt * 16 + rlo) * 128 + kg * 8;
        short8 a0 = *reinterpret_cast<const short8*>(ap);
        short8 a1 = *reinterpret_cast<const short8*>(ap + 32);
        short8 a2 = *reinterpret_cast<const short8*>(ap + 64);
        short8 a3 = *reinterpret_cast<const short8*>(ap + 96);
        f32x4 acc0 = {0.f, 0.f, 0.f, 0.f};
        f32x4 acc1 = {0.f, 0.f, 0.f, 0.f};
        acc0 = __builtin_amdgcn_mfma_f32_16x16x32_bf16(a0, b0[0], acc0, 0, 0, 0);
        acc1 = __builtin_amdgcn_mfma_f32_16x16x32_bf16(a0, b1[0], acc1, 0, 0, 0);
        acc0 = __builtin_amdgcn_mfma_f32_16x16x32_bf16(a1, b0[1], acc0, 0, 0, 0);
        acc1 = __builtin_amdgcn_mfma_f32_16x16x32_bf16(a1, b1[1], acc1, 0, 0, 0);
        acc0 = __builtin_amdgcn_mfma_f32_16x16x32_bf16(a2, b0[2], acc0, 0, 0, 0);
        acc1 = __builtin_amdgcn_mfma_f32_16x16x32_bf16(a2, b1[2], acc1, 0, 0, 0);
        acc0 = __builtin_amdgcn_mfma_f32_16x16x32_bf16(a3, b0[3], acc0, 0, 0, 0);
        acc1 = __builtin_amdgcn_mfma_f32_16x16x32_bf16(a3, b1[3], acc1, 0, 0, 0);
        int row0 = rt * 16 + kg * 4;
#pragma unroll
        for (int r = 0; r < 4; ++r) {
            float v0 = fmaxf(acc0[r] + bias0, 0.f);
            float v1 = fmaxf(acc1[r] + bias1, 0.f);
            unsigned int q = pk8x2(v0, v1);
            unsigned char* zr = zq_sl + (size_t)(row0 + r) * 384 + col0;
            zr[0] = (unsigned char)(q & 0xFFu);
            zr[16] = (unsigned char)((q >> 8) & 0xFFu);
            unsigned int w = pk8x2(v0 * pw0, v1 * pw1);
            unsigned char* wr = zqw_sl + (size_t)(row0 + r) * 384 + col0;
            wr[0] = (unsigned char)(w & 0xFFu);
            wr[16] = (unsigned char)((w >> 8) & 0xFFu);
        }
    }
}

// ---------- loss: fp8 MFMA diagonal dot; 16 pairs per wave; partial per block ----------
__global__ __launch_bounds__(256) void loss_mfma_kernel(
    const unsigned char* __restrict__ zq, const unsigned char* __restrict__ zqw,
    const int* __restrict__ pos, const int* __restrict__ neg,
    const float* __restrict__ pb, float* __restrict__ partialOut,
    int p, float inv_total) {
    __shared__ float red[4];
    int lane = threadIdx.x & 63;
    int wv = threadIdx.x >> 6;
    int pairBase = (blockIdx.x * 4 + wv) * 16;
    float term = 0.f;
    if (pairBase < 2 * p) {
        int m = lane & 15;
        int kg = lane >> 4;
        int pi = pairBase + m;
        int pic = (pi < 2 * p) ? pi : (2 * p - 1);
        bool isneg = (pic >= p);
        const int* pr = isneg ? neg : pos;
        int idx = isneg ? (pic - p) : pic;
        int a = pr[idx];
        int b = pr[p + idx];
        const long* pa = reinterpret_cast<const long*>(zq + (size_t)a * 384) + kg;
        const long* pbw = reinterpret_cast<const long*>(zqw + (size_t)b * 384) + kg;
        long av[12], bv[12];
#pragma unroll
        for (int s = 0; s < 12; ++s) av[s] = pa[s * 4];
#pragma unroll
        for (int s = 0; s < 12; ++s) bv[s] = pbw[s * 4];
        f32x4 acc = {0.f, 0.f, 0.f, 0.f};
#pragma unroll
        for (int s = 0; s < 12; ++s) {
            acc = __builtin_amdgcn_mfma_f32_16x16x32_fp8_fp8(av[s], bv[s], acc, 0, 0, 0);
        }
        bool isdiag = (lane >> 4) == ((lane & 15) >> 2);
        int r2 = lane & 3;
        float v = (r2 == 0) ? acc[0] : (r2 == 1) ? acc[1] : (r2 == 2) ? acc[2] : acc[3];
        if (isdiag && pi < 2 * p) {
            float logit = v * 0.125f + pb[0];
            float t = isneg ? logit : -logit;
            term = (fmaxf(t, 0.f) + log1pf(expf(-fabsf(t)))) * inv_total;
        }
    }
#pragma unroll
    for (int off = 1; off < 64; off <<= 1) term += __shfl_xor(term, off);
    if (lane == 0) red[wv] = term;
    __syncthreads();
    if (threadIdx.x == 0) partialOut[blockIdx.x] = red[0] + red[1] + red[2] + red[3];
}

__global__ __launch_bounds__(256) void loss_reduce_kernel(
    const float* __restrict__ partial, float* __restrict__ out, int m) {
    __shared__ float s[256];
    float a = 0.f;
    for (int i = threadIdx.x; i < m; i += 256) a += partial[i];
    s[threadIdx.x] = a;
    __syncthreads();
    for (int off = 128; off > 0; off >>= 1) {
        if (threadIdx.x < off) s[threadIdx.x] += s[threadIdx.x + off];
        __syncthreads();
    }
    if (threadIdx.x == 0) out[0] = s[0];
}

extern "C" void kernel_launch(void* const* d_in, const int* in_sizes, int n_in,
                              void* d_out, int out_size, void* d_ws, size_t ws_size,
                              hipStream_t stream) {
    const float* x      = (const float*)d_in[0];
    const int*   ei     = (const int*)d_in[1];
    const int*   pos    = (const int*)d_in[2];
    const int*   neg    = (const int*)d_in[3];
    const float* gcn_w  = (const float*)d_in[4];
    const float* gcn_b  = (const float*)d_in[5];
    const float* pred_w = (const float*)d_in[6];
    const float* pred_b = (const float*)d_in[7];
    float* out = (float*)d_out;

    const int n = in_sizes[0] / DD;     // 50000
    const int e = in_sizes[1] / 2;      // 640000
    const int p = in_sizes[2] / 2;      // 100000
    const int nbins = (n + 63) >> 6;    // 782

    char* ws = (char*)d_ws;
    size_t off = 0;
    auto alloc = [&](size_t bytes) {
        void* ptr = ws + off;
        off += (bytes + 255) & ~(size_t)255;
        return ptr;
    };
    float* dinv      = (float*)alloc((size_t)n * 4);
    int*   rowptr    = (int*)alloc((size_t)(n + 1) * 4);
    int*   binCounts = (int*)alloc((size_t)(nbins + 1) * 4);
    int*   binptr    = (int*)alloc((size_t)(nbins + 1) * 4);
    int*   binCur    = (int*)alloc((size_t)nbins * 4);
    float* lossPart  = (float*)alloc((size_t)4096 * 4);
    int*   csr_src   = (int*)alloc((size_t)e * 4);
    uint2* binEdges  = (uint2*)alloc((size_t)e * 8);
    ushort* wfrag    = (ushort*)alloc((size_t)3 * 2048 * 8 * 2);
    ushort* xh   = (ushort*)alloc((size_t)n * 128 * 2);
    ushort* aggh = (ushort*)alloc((size_t)n * 128 * 2);
    unsigned char* zq  = (unsigned char*)alloc((size_t)n * 384);
    unsigned char* zqw = (unsigned char*)alloc((size_t)n * 384);
    (void)ws_size;

    hipMemsetAsync(binCounts, 0, (size_t)(nbins + 1) * 4, stream);

    // binned CSR build
    bincount_kernel<<<(e + 255) / 256, 256, 0, stream>>>(ei + e, binCounts, e);
    binscan_kernel<<<1, 1024, 0, stream>>>(binCounts, binptr, binCur, rowptr, nbins, e, n);
    binfill_kernel<<<(e + 255) / 256, 256, 0, stream>>>(ei, binCur, binEdges, e);
    csr_from_bins_kernel<<<nbins, 256, 0, stream>>>(binEdges, binptr, rowptr, csr_src, n);
    dinv_kernel<<<(n + 255) / 256, 256, 0, stream>>>(dinv, rowptr, n);

    cvt_kernel<<<(int)(((size_t)n * 128 + 255) / 256), 256, 0, stream>>>(
        x, (__hip_bfloat16*)xh, (size_t)n * 128);
    wpack_kernel<<<24, 256, 0, stream>>>(gcn_w, wfrag);

    const int ntiles = n / 16;
    const int aggBlocks = (n * 64 + 255) / 256;
    for (int l = 0; l < 3; ++l) {
        if (l == 0) {
            aggregate_bf16_kernel<<<aggBlocks, 256, 0, stream>>>(
                xh, rowptr, csr_src, dinv, aggh, n);
        } else {
            aggregate_fp8_kernel<<<aggBlocks, 256, 0, stream>>>(
                zq + (size_t)(l - 1) * 128, rowptr, csr_src, dinv, aggh, n);
        }
        gemm_mfma_kernel<<<ntiles, 256, 0, stream>>>(
            aggh, wfrag + (size_t)l * 2048 * 8,
            gcn_b + (size_t)l * 128, pred_w + (size_t)l * 128,
            zq + (size_t)l * 128, zqw + (size_t)l * 128, ntiles);
    }

    float inv_total = 1.0f / (2.0f * (float)p);
    int lossBlocks = (2 * p + 63) / 64;  // 3125
    loss_mfma_kernel<<<lossBlocks, 256, 0, stream>>>(
        zq, zqw, pos, neg, pred_b, lossPart, p, inv_total);
    loss_reduce_kernel<<<1, 256, 0, stream>>>(lossPart, out, lossBlocks);
}

// Round 14
// 273.834 us; speedup vs baseline: 1.9004x; 1.9004x over previous
//
#include <hip/hip_runtime.h>
#include <hip/hip_bf16.h>

#define DD 128

typedef __attribute__((ext_vector_type(8))) short short8;
typedef __attribute__((ext_vector_type(4))) float f32x4;
typedef __attribute__((ext_vector_type(2))) float f32x2;

static __device__ __forceinline__ int gtid() {
    return blockIdx.x * blockDim.x + threadIdx.x;
}

static __device__ __forceinline__ ushort f2bfu(float f) {
    __hip_bfloat16 h = __float2bfloat16(f);
    return *reinterpret_cast<ushort*>(&h);
}

// ---- fp8 e4m3fn encode/decode (manual fallback, RNE, subnormal-correct) ----
static __device__ __forceinline__ unsigned int fp8e(float f) {
    unsigned int s = (__float_as_uint(f) >> 31) << 7;
    float a = fabsf(f);
    if (a < 0.015625f) return s | (unsigned int)rintf(a * 512.0f);
    unsigned int u = __float_as_uint(a);
    u += 0x0007FFFFu + ((u >> 20) & 1u);
    unsigned int e8 = (u >> 23) - 120u;
    unsigned int m = (u >> 20) & 7u;
    if (e8 > 15u || (e8 == 15u && m == 7u)) return s | 0x7Eu;
    return s | (e8 << 3) | m;
}

static __device__ __forceinline__ float fp8d(unsigned int b) {
    unsigned int t = b & 0x7Fu;
    float v = (t >= 8u) ? __uint_as_float((t << 20) + 0x3C000000u)
                        : (float)t * 0.001953125f;
    return (b & 0x80u) ? -v : v;
}

static __device__ __forceinline__ unsigned int pk8x2(float a, float b) {
#if __has_builtin(__builtin_amdgcn_cvt_pk_fp8_f32)
    return (unsigned int)__builtin_amdgcn_cvt_pk_fp8_f32(a, b, 0, false);
#else
    return fp8e(a) | (fp8e(b) << 8);
#endif
}

static __device__ __forceinline__ void fp8x4_dec(unsigned int u, float* f) {
#if __has_builtin(__builtin_amdgcn_cvt_pk_f32_fp8)
    f32x2 lo = __builtin_amdgcn_cvt_pk_f32_fp8((int)u, false);
    f32x2 hi = __builtin_amdgcn_cvt_pk_f32_fp8((int)u, true);
    f[0] = lo[0]; f[1] = lo[1]; f[2] = hi[0]; f[3] = hi[1];
#else
    f[0] = fp8d(u & 0xFFu);
    f[1] = fp8d((u >> 8) & 0xFFu);
    f[2] = fp8d((u >> 16) & 0xFFu);
    f[3] = fp8d((u >> 24) & 0xFFu);
#endif
}

// ---------- degree / CSR build (per-row cursors; low-contention atomics) ----------

__global__ void count_kernel(int* __restrict__ counts, const int* __restrict__ dst, int e) {
    int i = gtid();
    if (i < e) atomicAdd(&counts[dst[i]], 1);
}

__global__ void dinv_kernel(float* __restrict__ dinv, const int* __restrict__ counts, int n) {
    int i = gtid();
    if (i < n) dinv[i] = rsqrtf(1.0f + (float)counts[i]);
}

__global__ __launch_bounds__(256) void scan_blocks(const int* __restrict__ counts,
                                                   int* __restrict__ rowptr,
                                                   int* __restrict__ partial, int n) {
    __shared__ int s[256];
    int i = blockIdx.x * 256 + threadIdx.x;
    int v = (i < n) ? counts[i] : 0;
    s[threadIdx.x] = v;
    __syncthreads();
    for (int off = 1; off < 256; off <<= 1) {
        int t = (threadIdx.x >= off) ? s[threadIdx.x - off] : 0;
        __syncthreads();
        s[threadIdx.x] += t;
        __syncthreads();
    }
    if (i < n) rowptr[i] = s[threadIdx.x] - v;
    if (threadIdx.x == 255) partial[blockIdx.x] = s[255];
}

__global__ __launch_bounds__(256) void scan_partials(int* __restrict__ partial,
                                                     int* __restrict__ partial2, int nb) {
    __shared__ int s[256];
    int v = (threadIdx.x < nb) ? partial[threadIdx.x] : 0;
    s[threadIdx.x] = v;
    __syncthreads();
    for (int off = 1; off < 256; off <<= 1) {
        int t = (threadIdx.x >= off) ? s[threadIdx.x - off] : 0;
        __syncthreads();
        s[threadIdx.x] += t;
        __syncthreads();
    }
    partial2[threadIdx.x] = s[threadIdx.x] - v;
}

__global__ __launch_bounds__(256) void add_offsets(int* __restrict__ rowptr,
                                                   int* __restrict__ cursor,
                                                   const int* __restrict__ partial2,
                                                   int n, int e) {
    int i = blockIdx.x * 256 + threadIdx.x;
    if (i < n) {
        int r = rowptr[i] + partial2[blockIdx.x];
        rowptr[i] = r;
        cursor[i] = r;
        if (i == n - 1) rowptr[n] = e;
    }
}

__global__ void fill_kernel(const int* __restrict__ ei, int* __restrict__ cursor,
                            int* __restrict__ csr_src, int e) {
    int i = gtid();
    if (i >= e) return;
    int s = ei[i];
    int d = ei[e + i];
    int pos = atomicAdd(&cursor[d], 1);
    csr_src[pos] = s;
}

// ---------- x -> bf16 (vectorized: 8 elems/thread) ----------
__global__ void cvt_kernel(const float* __restrict__ x, ushort* __restrict__ xh, size_t m8) {
    size_t i = (size_t)blockIdx.x * blockDim.x + threadIdx.x;
    if (i >= m8) return;
    const float4* xp = reinterpret_cast<const float4*>(x + i * 8);
    float4 a = xp[0], b = xp[1];
    unsigned int pk[4];
    pk[0] = (unsigned int)f2bfu(a.x) | ((unsigned int)f2bfu(a.y) << 16);
    pk[1] = (unsigned int)f2bfu(a.z) | ((unsigned int)f2bfu(a.w) << 16);
    pk[2] = (unsigned int)f2bfu(b.x) | ((unsigned int)f2bfu(b.y) << 16);
    pk[3] = (unsigned int)f2bfu(b.z) | ((unsigned int)f2bfu(b.w) << 16);
    *reinterpret_cast<uint4*>(xh + i * 8) = *reinterpret_cast<const uint4*>(pk);
}

// ---------- W -> bf16 MFMA B-fragment order ----------
__global__ __launch_bounds__(256) void wpack_kernel(const float* __restrict__ gcn_w,
                                                    ushort* __restrict__ wfrag) {
    int tid = blockIdx.x * 256 + threadIdx.x;
    if (tid >= 3 * 4 * 8 * 64) return;
    int lane = tid & 63;
    int c = (tid >> 6) & 7;
    int s = (tid >> 9) & 3;
    int l = tid >> 11;
    const float* W = gcn_w + (size_t)l * 128 * 128;
    int col = c * 16 + (lane & 15);
    int k0 = s * 32 + (lane >> 4) * 8;
    ushort u[8];
#pragma unroll
    for (int j = 0; j < 8; ++j) {
        u[j] = f2bfu(W[(size_t)(k0 + j) * 128 + col]);
    }
    *reinterpret_cast<uint4*>(wfrag + (size_t)tid * 8) = *reinterpret_cast<const uint4*>(u);
}

// ---------- aggregate-first (no bias/relu): aggh = Ah ----------

// layer-0: bf16 source [n][128]; 4 edge slots x 16 chunks
__global__ __launch_bounds__(256) void aggregate_bf16_kernel(
    const ushort* __restrict__ src, const int* __restrict__ rowptr,
    const int* __restrict__ csr_src, const float* __restrict__ dinv,
    ushort* __restrict__ aggh, int n) {
    int gid = gtid();
    int row = gid >> 6;
    if (row >= n) return;
    int lane = threadIdx.x & 63;
    int g = lane >> 4;
    int c = lane & 15;
    int j0 = rowptr[row], j1 = rowptr[row + 1];
    float dr = dinv[row];
    float acc[8] = {0.f, 0.f, 0.f, 0.f, 0.f, 0.f, 0.f, 0.f};
    for (int j = j0 + g; j < j1; j += 4) {
        int s = csr_src[j];
        float cf = dinv[s] * dr;
        uint4 v = *reinterpret_cast<const uint4*>(src + (size_t)s * 128 + c * 8);
        const unsigned int* u = (const unsigned int*)&v;
#pragma unroll
        for (int q = 0; q < 4; ++q) {
            acc[2 * q] = fmaf(cf, __uint_as_float(u[q] << 16), acc[2 * q]);
            acc[2 * q + 1] = fmaf(cf, __uint_as_float(u[q] & 0xffff0000u), acc[2 * q + 1]);
        }
    }
#pragma unroll
    for (int k = 0; k < 8; ++k) {
        acc[k] += __shfl_xor(acc[k], 16);
        acc[k] += __shfl_xor(acc[k], 32);
    }
    float d2 = dr * dr;
    uint4 sv = *reinterpret_cast<const uint4*>(src + (size_t)row * 128 + c * 8);
    const unsigned int* su = (const unsigned int*)&sv;
#pragma unroll
    for (int q = 0; q < 4; ++q) {
        acc[2 * q] = fmaf(d2, __uint_as_float(su[q] << 16), acc[2 * q]);
        acc[2 * q + 1] = fmaf(d2, __uint_as_float(su[q] & 0xffff0000u), acc[2 * q + 1]);
    }
    if (g == 0) {
        unsigned int pk[4];
#pragma unroll
        for (int q = 0; q < 4; ++q) {
            pk[q] = (unsigned int)f2bfu(acc[2 * q]) | ((unsigned int)f2bfu(acc[2 * q + 1]) << 16);
        }
        *reinterpret_cast<uint4*>(aggh + (size_t)row * 128 + c * 8) =
            *reinterpret_cast<const uint4*>(pk);
    }
}

// layer>=1: fp8 source slice of zq (row stride 384); 8 edge slots x 8 chunks (16 feats)
__global__ __launch_bounds__(256) void aggregate_fp8_kernel(
    const unsigned char* __restrict__ srcq, const int* __restrict__ rowptr,
    const int* __restrict__ csr_src, const float* __restrict__ dinv,
    ushort* __restrict__ aggh, int n) {
    int gid = gtid();
    int row = gid >> 6;
    if (row >= n) return;
    int lane = threadIdx.x & 63;
    int g = lane >> 3;   // edge slot 0..7
    int c = lane & 7;    // feature chunk (16 feats)
    int j0 = rowptr[row], j1 = rowptr[row + 1];
    float dr = dinv[row];
    float acc[16];
#pragma unroll
    for (int k = 0; k < 16; ++k) acc[k] = 0.f;
    for (int j = j0 + g; j < j1; j += 8) {
        int s = csr_src[j];
        float cf = dinv[s] * dr;
        uint4 v = *reinterpret_cast<const uint4*>(srcq + (size_t)s * 384 + c * 16);
        float f[16];
        fp8x4_dec(v.x, f);
        fp8x4_dec(v.y, f + 4);
        fp8x4_dec(v.z, f + 8);
        fp8x4_dec(v.w, f + 12);
#pragma unroll
        for (int k = 0; k < 16; ++k) acc[k] = fmaf(cf, f[k], acc[k]);
    }
#pragma unroll
    for (int k = 0; k < 16; ++k) {
        acc[k] += __shfl_xor(acc[k], 8);
        acc[k] += __shfl_xor(acc[k], 16);
        acc[k] += __shfl_xor(acc[k], 32);
    }
    float d2 = dr * dr;
    uint4 sv = *reinterpret_cast<const uint4*>(srcq + (size_t)row * 384 + c * 16);
    float sf[16];
    fp8x4_dec(sv.x, sf);
    fp8x4_dec(sv.y, sf + 4);
    fp8x4_dec(sv.z, sf + 8);
    fp8x4_dec(sv.w, sf + 12);
#pragma unroll
    for (int k = 0; k < 16; ++k) acc[k] = fmaf(d2, sf[k], acc[k]);
    if (g == 0) {
        unsigned int pk[8];
#pragma unroll
        for (int q = 0; q < 8; ++q) {
            pk[q] = (unsigned int)f2bfu(acc[2 * q]) | ((unsigned int)f2bfu(acc[2 * q + 1]) << 16);
        }
        ushort* ap = aggh + (size_t)row * 128 + c * 16;
        *reinterpret_cast<uint4*>(ap) = *reinterpret_cast<const uint4*>(pk);
        *reinterpret_cast<uint4*>(ap + 8) = *reinterpret_cast<const uint4*>(pk + 4);
    }
}

// ---------- MFMA GEMM: aggh @ W + bias -> relu -> zq (fp8) + zqw (fp8*pw*8) ----------
__global__ __launch_bounds__(256) void gemm_mfma_kernel(
    const ushort* __restrict__ aggh, const ushort* __restrict__ wfrag,
    const float* __restrict__ bias, const float* __restrict__ pwsl,
    unsigned char* __restrict__ zq_sl, unsigned char* __restrict__ zqw_sl, int ntiles) {
    int lane = threadIdx.x & 63;
    int wv = threadIdx.x >> 6;
    short8 b0[4], b1[4];
    int c0 = wv * 2;
#pragma unroll
    for (int s = 0; s < 4; ++s) {
        b0[s] = *reinterpret_cast<const short8*>(wfrag + ((size_t)(s * 8 + c0) * 64 + lane) * 8);
        b1[s] = *reinterpret_cast<const short8*>(wfrag + ((size_t)(s * 8 + c0 + 1) * 64 + lane) * 8);
    }
    int rlo = lane & 15;
    int kg = lane >> 4;
    int col0 = wv * 32 + rlo;
    int col1 = col0 + 16;
    float bias0 = bias[col0], bias1 = bias[col1];
    float pw0 = pwsl[col0] * 8.0f, pw1 = pwsl[col1] * 8.0f;
    for (int rt = blockIdx.x; rt < ntiles; rt += gridDim.x) {
        const ushort* ap = aggh + (size_t)(rt * 16 + rlo) * 128 + kg * 8;
        short8 a0 = *reinterpret_cast<const short8*>(ap);
        short8 a1 = *reinterpret_cast<const short8*>(ap + 32);
        short8 a2 = *reinterpret_cast<const short8*>(ap + 64);
        short8 a3 = *reinterpret_cast<const short8*>(ap + 96);
        f32x4 acc0 = {0.f, 0.f, 0.f, 0.f};
        f32x4 acc1 = {0.f, 0.f, 0.f, 0.f};
        acc0 = __builtin_amdgcn_mfma_f32_16x16x32_bf16(a0, b0[0], acc0, 0, 0, 0);
        acc1 = __builtin_amdgcn_mfma_f32_16x16x32_bf16(a0, b1[0], acc1, 0, 0, 0);
        acc0 = __builtin_amdgcn_mfma_f32_16x16x32_bf16(a1, b0[1], acc0, 0, 0, 0);
        acc1 = __builtin_amdgcn_mfma_f32_16x16x32_bf16(a1, b1[1], acc1, 0, 0, 0);
        acc0 = __builtin_amdgcn_mfma_f32_16x16x32_bf16(a2, b0[2], acc0, 0, 0, 0);
        acc1 = __builtin_amdgcn_mfma_f32_16x16x32_bf16(a2, b1[2], acc1, 0, 0, 0);
        acc0 = __builtin_amdgcn_mfma_f32_16x16x32_bf16(a3, b0[3], acc0, 0, 0, 0);
        acc1 = __builtin_amdgcn_mfma_f32_16x16x32_bf16(a3, b1[3], acc1, 0, 0, 0);
        int row0 = rt * 16 + kg * 4;
#pragma unroll
        for (int r = 0; r < 4; ++r) {
            float v0 = fmaxf(acc0[r] + bias0, 0.f);
            float v1 = fmaxf(acc1[r] + bias1, 0.f);
            unsigned int q = pk8x2(v0, v1);
            unsigned char* zr = zq_sl + (size_t)(row0 + r) * 384 + col0;
            zr[0] = (unsigned char)(q & 0xFFu);
            zr[16] = (unsigned char)((q >> 8) & 0xFFu);
            unsigned int w = pk8x2(v0 * pw0, v1 * pw1);
            unsigned char* wr = zqw_sl + (size_t)(row0 + r) * 384 + col0;
            wr[0] = (unsigned char)(w & 0xFFu);
            wr[16] = (unsigned char)((w >> 8) & 0xFFu);
        }
    }
}

// ---------- loss: fp8 MFMA diagonal dot; 16 pairs per wave; partial per block ----------
__global__ __launch_bounds__(256) void loss_mfma_kernel(
    const unsigned char* __restrict__ zq, const unsigned char* __restrict__ zqw,
    const int* __restrict__ pos, const int* __restrict__ neg,
    const float* __restrict__ pb, float* __restrict__ partialOut,
    int p, float inv_total) {
    __shared__ float red[4];
    int lane = threadIdx.x & 63;
    int wv = threadIdx.x >> 6;
    int pairBase = (blockIdx.x * 4 + wv) * 16;
    float term = 0.f;
    if (pairBase < 2 * p) {
        int m = lane & 15;
        int kg = lane >> 4;
        int pi = pairBase + m;
        int pic = (pi < 2 * p) ? pi : (2 * p - 1);
        bool isneg = (pic >= p);
        const int* pr = isneg ? neg : pos;
        int idx = isneg ? (pic - p) : pic;
        int a = pr[idx];
        int b = pr[p + idx];
        const long* pa = reinterpret_cast<const long*>(zq + (size_t)a * 384) + kg;
        const long* pbw = reinterpret_cast<const long*>(zqw + (size_t)b * 384) + kg;
        long av[12], bv[12];
#pragma unroll
        for (int s = 0; s < 12; ++s) av[s] = pa[s * 4];
#pragma unroll
        for (int s = 0; s < 12; ++s) bv[s] = pbw[s * 4];
        f32x4 acc = {0.f, 0.f, 0.f, 0.f};
#pragma unroll
        for (int s = 0; s < 12; ++s) {
            acc = __builtin_amdgcn_mfma_f32_16x16x32_fp8_fp8(av[s], bv[s], acc, 0, 0, 0);
        }
        bool isdiag = (lane >> 4) == ((lane & 15) >> 2);
        int r2 = lane & 3;
        float v = (r2 == 0) ? acc[0] : (r2 == 1) ? acc[1] : (r2 == 2) ? acc[2] : acc[3];
        if (isdiag && pi < 2 * p) {
            float logit = v * 0.125f + pb[0];
            float t = isneg ? logit : -logit;
            term = (fmaxf(t, 0.f) + log1pf(expf(-fabsf(t)))) * inv_total;
        }
    }
#pragma unroll
    for (int off = 1; off < 64; off <<= 1) term += __shfl_xor(term, off);
    if (lane == 0) red[wv] = term;
    __syncthreads();
    if (threadIdx.x == 0) partialOut[blockIdx.x] = red[0] + red[1] + red[2] + red[3];
}

__global__ __launch_bounds__(256) void loss_reduce_kernel(
    const float* __restrict__ partial, float* __restrict__ out, int m) {
    __shared__ float s[256];
    float a = 0.f;
    for (int i = threadIdx.x; i < m; i += 256) a += partial[i];
    s[threadIdx.x] = a;
    __syncthreads();
    for (int off = 128; off > 0; off >>= 1) {
        if (threadIdx.x < off) s[threadIdx.x] += s[threadIdx.x + off];
        __syncthreads();
    }
    if (threadIdx.x == 0) out[0] = s[0];
}

extern "C" void kernel_launch(void* const* d_in, const int* in_sizes, int n_in,
                              void* d_out, int out_size, void* d_ws, size_t ws_size,
                              hipStream_t stream) {
    const float* x      = (const float*)d_in[0];
    const int*   ei     = (const int*)d_in[1];
    const int*   pos    = (const int*)d_in[2];
    const int*   neg    = (const int*)d_in[3];
    const float* gcn_w  = (const float*)d_in[4];
    const float* gcn_b  = (const float*)d_in[5];
    const float* pred_w = (const float*)d_in[6];
    const float* pred_b = (const float*)d_in[7];
    float* out = (float*)d_out;

    const int n = in_sizes[0] / DD;     // 50000
    const int e = in_sizes[1] / 2;      // 640000
    const int p = in_sizes[2] / 2;      // 100000
    const int nb = (n + 255) / 256;

    char* ws = (char*)d_ws;
    size_t off = 0;
    auto alloc = [&](size_t bytes) {
        void* ptr = ws + off;
        off += (bytes + 255) & ~(size_t)255;
        return ptr;
    };
    float* dinv      = (float*)alloc((size_t)n * 4);
    int*   counts    = (int*)alloc((size_t)n * 4);
    int*   rowptr    = (int*)alloc((size_t)(n + 1) * 4);
    int*   cursor    = (int*)alloc((size_t)n * 4);
    int*   partial   = (int*)alloc(256 * 4);
    int*   partial2  = (int*)alloc(256 * 4);
    float* lossPart  = (float*)alloc((size_t)4096 * 4);
    int*   csr_src   = (int*)alloc((size_t)e * 4);
    ushort* wfrag    = (ushort*)alloc((size_t)3 * 2048 * 8 * 2);
    ushort* xh   = (ushort*)alloc((size_t)n * 128 * 2);
    ushort* aggh = (ushort*)alloc((size_t)n * 128 * 2);
    unsigned char* zq  = (unsigned char*)alloc((size_t)n * 384);
    unsigned char* zqw = (unsigned char*)alloc((size_t)n * 384);
    (void)ws_size;

    hipMemsetAsync(counts, 0, (size_t)n * 4, stream);

    count_kernel<<<(e + 255) / 256, 256, 0, stream>>>(counts, ei + e, e);
    dinv_kernel<<<nb, 256, 0, stream>>>(dinv, counts, n);
    scan_blocks<<<nb, 256, 0, stream>>>(counts, rowptr, partial, n);
    scan_partials<<<1, 256, 0, stream>>>(partial, partial2, nb);
    add_offsets<<<nb, 256, 0, stream>>>(rowptr, cursor, partial2, n, e);
    fill_kernel<<<(e + 255) / 256, 256, 0, stream>>>(ei, cursor, csr_src, e);

    size_t m8 = (size_t)n * 128 / 8;
    cvt_kernel<<<(int)((m8 + 255) / 256), 256, 0, stream>>>(x, xh, m8);
    wpack_kernel<<<24, 256, 0, stream>>>(gcn_w, wfrag);

    const int ntiles = n / 16;
    const int aggBlocks = (n * 64 + 255) / 256;
    for (int l = 0; l < 3; ++l) {
        if (l == 0) {
            aggregate_bf16_kernel<<<aggBlocks, 256, 0, stream>>>(
                xh, rowptr, csr_src, dinv, aggh, n);
        } else {
            aggregate_fp8_kernel<<<aggBlocks, 256, 0, stream>>>(
                zq + (size_t)(l - 1) * 128, rowptr, csr_src, dinv, aggh, n);
        }
        gemm_mfma_kernel<<<ntiles, 256, 0, stream>>>(
            aggh, wfrag + (size_t)l * 2048 * 8,
            gcn_b + (size_t)l * 128, pred_w + (size_t)l * 128,
            zq + (size_t)l * 128, zqw + (size_t)l * 128, ntiles);
    }

    float inv_total = 1.0f / (2.0f * (float)p);
    int lossBlocks = (2 * p + 63) / 64;  // 3125
    loss_mfma_kernel<<<lossBlocks, 256, 0, stream>>>(
        zq, zqw, pos, neg, pred_b, lossPart, p, inv_total);
    loss_reduce_kernel<<<1, 256, 0, stream>>>(lossPart, out, lossBlocks);
}

// Round 15
// 268.503 us; speedup vs baseline: 1.9381x; 1.0199x over previous
//
#include <hip/hip_runtime.h>
#include <hip/hip_bf16.h>

#define DD 128

typedef __attribute__((ext_vector_type(8))) short short8;
typedef __attribute__((ext_vector_type(4))) float f32x4;
typedef __attribute__((ext_vector_type(2))) float f32x2;

static __device__ __forceinline__ int gtid() {
    return blockIdx.x * blockDim.x + threadIdx.x;
}

static __device__ __forceinline__ ushort f2bfu(float f) {
    __hip_bfloat16 h = __float2bfloat16(f);
    return *reinterpret_cast<ushort*>(&h);
}

// ---- fp8 e4m3fn encode/decode (manual fallback, RNE, subnormal-correct) ----
static __device__ __forceinline__ unsigned int fp8e(float f) {
    unsigned int s = (__float_as_uint(f) >> 31) << 7;
    float a = fabsf(f);
    if (a < 0.015625f) return s | (unsigned int)rintf(a * 512.0f);
    unsigned int u = __float_as_uint(a);
    u += 0x0007FFFFu + ((u >> 20) & 1u);
    unsigned int e8 = (u >> 23) - 120u;
    unsigned int m = (u >> 20) & 7u;
    if (e8 > 15u || (e8 == 15u && m == 7u)) return s | 0x7Eu;
    return s | (e8 << 3) | m;
}

static __device__ __forceinline__ float fp8d(unsigned int b) {
    unsigned int t = b & 0x7Fu;
    float v = (t >= 8u) ? __uint_as_float((t << 20) + 0x3C000000u)
                        : (float)t * 0.001953125f;
    return (b & 0x80u) ? -v : v;
}

static __device__ __forceinline__ unsigned int pk8x2(float a, float b) {
#if __has_builtin(__builtin_amdgcn_cvt_pk_fp8_f32)
    return (unsigned int)__builtin_amdgcn_cvt_pk_fp8_f32(a, b, 0, false);
#else
    return fp8e(a) | (fp8e(b) << 8);
#endif
}

static __device__ __forceinline__ void fp8x4_dec(unsigned int u, float* f) {
#if __has_builtin(__builtin_amdgcn_cvt_pk_f32_fp8)
    f32x2 lo = __builtin_amdgcn_cvt_pk_f32_fp8((int)u, false);
    f32x2 hi = __builtin_amdgcn_cvt_pk_f32_fp8((int)u, true);
    f[0] = lo[0]; f[1] = lo[1]; f[2] = hi[0]; f[3] = hi[1];
#else
    f[0] = fp8d(u & 0xFFu);
    f[1] = fp8d((u >> 8) & 0xFFu);
    f[2] = fp8d((u >> 16) & 0xFFu);
    f[3] = fp8d((u >> 24) & 0xFFu);
#endif
}

// ---------- degree / CSR build (per-row cursors; ushort src entries) ----------

__global__ void count_kernel(int* __restrict__ counts, const int* __restrict__ dst, int e) {
    int i = gtid();
    if (i < e) atomicAdd(&counts[dst[i]], 1);
}

__global__ void dinv_kernel(float* __restrict__ dinv, const int* __restrict__ counts, int n) {
    int i = gtid();
    if (i < n) dinv[i] = rsqrtf(1.0f + (float)counts[i]);
}

__global__ __launch_bounds__(256) void scan_blocks(const int* __restrict__ counts,
                                                   int* __restrict__ rowptr,
                                                   int* __restrict__ partial, int n) {
    __shared__ int s[256];
    int i = blockIdx.x * 256 + threadIdx.x;
    int v = (i < n) ? counts[i] : 0;
    s[threadIdx.x] = v;
    __syncthreads();
    for (int off = 1; off < 256; off <<= 1) {
        int t = (threadIdx.x >= off) ? s[threadIdx.x - off] : 0;
        __syncthreads();
        s[threadIdx.x] += t;
        __syncthreads();
    }
    if (i < n) rowptr[i] = s[threadIdx.x] - v;
    if (threadIdx.x == 255) partial[blockIdx.x] = s[255];
}

__global__ __launch_bounds__(256) void scan_partials(int* __restrict__ partial,
                                                     int* __restrict__ partial2, int nb) {
    __shared__ int s[256];
    int v = (threadIdx.x < nb) ? partial[threadIdx.x] : 0;
    s[threadIdx.x] = v;
    __syncthreads();
    for (int off = 1; off < 256; off <<= 1) {
        int t = (threadIdx.x >= off) ? s[threadIdx.x - off] : 0;
        __syncthreads();
        s[threadIdx.x] += t;
        __syncthreads();
    }
    partial2[threadIdx.x] = s[threadIdx.x] - v;
}

__global__ __launch_bounds__(256) void add_offsets(int* __restrict__ rowptr,
                                                   int* __restrict__ cursor,
                                                   const int* __restrict__ partial2,
                                                   int n, int e) {
    int i = blockIdx.x * 256 + threadIdx.x;
    if (i < n) {
        int r = rowptr[i] + partial2[blockIdx.x];
        rowptr[i] = r;
        cursor[i] = r;
        if (i == n - 1) rowptr[n] = e;
    }
}

// ushort src entries: halves scattered-write footprint (n < 65536)
__global__ void fill_kernel(const int* __restrict__ ei, int* __restrict__ cursor,
                            ushort* __restrict__ csr_src, int e) {
    int i = gtid();
    if (i >= e) return;
    int s = ei[i];
    int d = ei[e + i];
    int pos = atomicAdd(&cursor[d], 1);
    csr_src[pos] = (ushort)s;
}

// ---------- x -> bf16 (vectorized: 8 elems/thread) ----------
__global__ void cvt_kernel(const float* __restrict__ x, ushort* __restrict__ xh, size_t m8) {
    size_t i = (size_t)blockIdx.x * blockDim.x + threadIdx.x;
    if (i >= m8) return;
    const float4* xp = reinterpret_cast<const float4*>(x + i * 8);
    float4 a = xp[0], b = xp[1];
    unsigned int pk[4];
    pk[0] = (unsigned int)f2bfu(a.x) | ((unsigned int)f2bfu(a.y) << 16);
    pk[1] = (unsigned int)f2bfu(a.z) | ((unsigned int)f2bfu(a.w) << 16);
    pk[2] = (unsigned int)f2bfu(b.x) | ((unsigned int)f2bfu(b.y) << 16);
    pk[3] = (unsigned int)f2bfu(b.z) | ((unsigned int)f2bfu(b.w) << 16);
    *reinterpret_cast<uint4*>(xh + i * 8) = *reinterpret_cast<const uint4*>(pk);
}

// ---------- W -> bf16 MFMA B-fragment order ----------
__global__ __launch_bounds__(256) void wpack_kernel(const float* __restrict__ gcn_w,
                                                    ushort* __restrict__ wfrag) {
    int tid = blockIdx.x * 256 + threadIdx.x;
    if (tid >= 3 * 4 * 8 * 64) return;
    int lane = tid & 63;
    int c = (tid >> 6) & 7;
    int s = (tid >> 9) & 3;
    int l = tid >> 11;
    const float* W = gcn_w + (size_t)l * 128 * 128;
    int col = c * 16 + (lane & 15);
    int k0 = s * 32 + (lane >> 4) * 8;
    ushort u[8];
#pragma unroll
    for (int j = 0; j < 8; ++j) {
        u[j] = f2bfu(W[(size_t)(k0 + j) * 128 + col]);
    }
    *reinterpret_cast<uint4*>(wfrag + (size_t)tid * 8) = *reinterpret_cast<const uint4*>(u);
}

// ---------- aggregate-first (no bias/relu): aggh = Ah ----------

// layer-0: bf16 source [n][128]; 4 edge slots x 16 chunks
__global__ __launch_bounds__(256) void aggregate_bf16_kernel(
    const ushort* __restrict__ src, const int* __restrict__ rowptr,
    const ushort* __restrict__ csr_src, const float* __restrict__ dinv,
    ushort* __restrict__ aggh, int n) {
    int gid = gtid();
    int row = gid >> 6;
    if (row >= n) return;
    int lane = threadIdx.x & 63;
    int g = lane >> 4;
    int c = lane & 15;
    int j0 = rowptr[row], j1 = rowptr[row + 1];
    float dr = dinv[row];
    float acc[8] = {0.f, 0.f, 0.f, 0.f, 0.f, 0.f, 0.f, 0.f};
    for (int j = j0 + g; j < j1; j += 4) {
        int s = (int)csr_src[j];
        float cf = dinv[s] * dr;
        uint4 v = *reinterpret_cast<const uint4*>(src + (size_t)s * 128 + c * 8);
        const unsigned int* u = (const unsigned int*)&v;
#pragma unroll
        for (int q = 0; q < 4; ++q) {
            acc[2 * q] = fmaf(cf, __uint_as_float(u[q] << 16), acc[2 * q]);
            acc[2 * q + 1] = fmaf(cf, __uint_as_float(u[q] & 0xffff0000u), acc[2 * q + 1]);
        }
    }
#pragma unroll
    for (int k = 0; k < 8; ++k) {
        acc[k] += __shfl_xor(acc[k], 16);
        acc[k] += __shfl_xor(acc[k], 32);
    }
    float d2 = dr * dr;
    uint4 sv = *reinterpret_cast<const uint4*>(src + (size_t)row * 128 + c * 8);
    const unsigned int* su = (const unsigned int*)&sv;
#pragma unroll
    for (int q = 0; q < 4; ++q) {
        acc[2 * q] = fmaf(d2, __uint_as_float(su[q] << 16), acc[2 * q]);
        acc[2 * q + 1] = fmaf(d2, __uint_as_float(su[q] & 0xffff0000u), acc[2 * q + 1]);
    }
    if (g == 0) {
        unsigned int pk[4];
#pragma unroll
        for (int q = 0; q < 4; ++q) {
            pk[q] = (unsigned int)f2bfu(acc[2 * q]) | ((unsigned int)f2bfu(acc[2 * q + 1]) << 16);
        }
        *reinterpret_cast<uint4*>(aggh + (size_t)row * 128 + c * 8) =
            *reinterpret_cast<const uint4*>(pk);
    }
}

// layer>=1: fp8 source slice of zq (row stride 384); 8 edge slots x 8 chunks (16 feats)
__global__ __launch_bounds__(256) void aggregate_fp8_kernel(
    const unsigned char* __restrict__ srcq, const int* __restrict__ rowptr,
    const ushort* __restrict__ csr_src, const float* __restrict__ dinv,
    ushort* __restrict__ aggh, int n) {
    int gid = gtid();
    int row = gid >> 6;
    if (row >= n) return;
    int lane = threadIdx.x & 63;
    int g = lane >> 3;   // edge slot 0..7
    int c = lane & 7;    // feature chunk (16 feats)
    int j0 = rowptr[row], j1 = rowptr[row + 1];
    float dr = dinv[row];
    float acc[16];
#pragma unroll
    for (int k = 0; k < 16; ++k) acc[k] = 0.f;
    for (int j = j0 + g; j < j1; j += 8) {
        int s = (int)csr_src[j];
        float cf = dinv[s] * dr;
        uint4 v = *reinterpret_cast<const uint4*>(srcq + (size_t)s * 384 + c * 16);
        float f[16];
        fp8x4_dec(v.x, f);
        fp8x4_dec(v.y, f + 4);
        fp8x4_dec(v.z, f + 8);
        fp8x4_dec(v.w, f + 12);
#pragma unroll
        for (int k = 0; k < 16; ++k) acc[k] = fmaf(cf, f[k], acc[k]);
    }
#pragma unroll
    for (int k = 0; k < 16; ++k) {
        acc[k] += __shfl_xor(acc[k], 8);
        acc[k] += __shfl_xor(acc[k], 16);
        acc[k] += __shfl_xor(acc[k], 32);
    }
    float d2 = dr * dr;
    uint4 sv = *reinterpret_cast<const uint4*>(srcq + (size_t)row * 384 + c * 16);
    float sf[16];
    fp8x4_dec(sv.x, sf);
    fp8x4_dec(sv.y, sf + 4);
    fp8x4_dec(sv.z, sf + 8);
    fp8x4_dec(sv.w, sf + 12);
#pragma unroll
    for (int k = 0; k < 16; ++k) acc[k] = fmaf(d2, sf[k], acc[k]);
    if (g == 0) {
        unsigned int pk[8];
#pragma unroll
        for (int q = 0; q < 8; ++q) {
            pk[q] = (unsigned int)f2bfu(acc[2 * q]) | ((unsigned int)f2bfu(acc[2 * q + 1]) << 16);
        }
        ushort* ap = aggh + (size_t)row * 128 + c * 16;
        *reinterpret_cast<uint4*>(ap) = *reinterpret_cast<const uint4*>(pk);
        *reinterpret_cast<uint4*>(ap + 8) = *reinterpret_cast<const uint4*>(pk + 4);
    }
}

// ---------- MFMA GEMM: aggh @ W + bias -> relu -> zq (fp8) + zqw (fp8*pw*8) ----------
__global__ __launch_bounds__(256) void gemm_mfma_kernel(
    const ushort* __restrict__ aggh, const ushort* __restrict__ wfrag,
    const float* __restrict__ bias, const float* __restrict__ pwsl,
    unsigned char* __restrict__ zq_sl, unsigned char* __restrict__ zqw_sl, int ntiles) {
    int lane = threadIdx.x & 63;
    int wv = threadIdx.x >> 6;
    short8 b0[4], b1[4];
    int c0 = wv * 2;
#pragma unroll
    for (int s = 0; s < 4; ++s) {
        b0[s] = *reinterpret_cast<const short8*>(wfrag + ((size_t)(s * 8 + c0) * 64 + lane) * 8);
        b1[s] = *reinterpret_cast<const short8*>(wfrag + ((size_t)(s * 8 + c0 + 1) * 64 + lane) * 8);
    }
    int rlo = lane & 15;
    int kg = lane >> 4;
    int col0 = wv * 32 + rlo;
    int col1 = col0 + 16;
    float bias0 = bias[col0], bias1 = bias[col1];
    float pw0 = pwsl[col0] * 8.0f, pw1 = pwsl[col1] * 8.0f;
    for (int rt = blockIdx.x; rt < ntiles; rt += gridDim.x) {
        const ushort* ap = aggh + (size_t)(rt * 16 + rlo) * 128 + kg * 8;
        short8 a0 = *reinterpret_cast<const short8*>(ap);
        short8 a1 = *reinterpret_cast<const short8*>(ap + 32);
        short8 a2 = *reinterpret_cast<const short8*>(ap + 64);
        short8 a3 = *reinterpret_cast<const short8*>(ap + 96);
        f32x4 acc0 = {0.f, 0.f, 0.f, 0.f};
        f32x4 acc1 = {0.f, 0.f, 0.f, 0.f};
        acc0 = __builtin_amdgcn_mfma_f32_16x16x32_bf16(a0, b0[0], acc0, 0, 0, 0);
        acc1 = __builtin_amdgcn_mfma_f32_16x16x32_bf16(a0, b1[0], acc1, 0, 0, 0);
        acc0 = __builtin_amdgcn_mfma_f32_16x16x32_bf16(a1, b0[1], acc0, 0, 0, 0);
        acc1 = __builtin_amdgcn_mfma_f32_16x16x32_bf16(a1, b1[1], acc1, 0, 0, 0);
        acc0 = __builtin_amdgcn_mfma_f32_16x16x32_bf16(a2, b0[2], acc0, 0, 0, 0);
        acc1 = __builtin_amdgcn_mfma_f32_16x16x32_bf16(a2, b1[2], acc1, 0, 0, 0);
        acc0 = __builtin_amdgcn_mfma_f32_16x16x32_bf16(a3, b0[3], acc0, 0, 0, 0);
        acc1 = __builtin_amdgcn_mfma_f32_16x16x32_bf16(a3, b1[3], acc1, 0, 0, 0);
        int row0 = rt * 16 + kg * 4;
#pragma unroll
        for (int r = 0; r < 4; ++r) {
            float v0 = fmaxf(acc0[r] + bias0, 0.f);
            float v1 = fmaxf(acc1[r] + bias1, 0.f);
            unsigned int q = pk8x2(v0, v1);
            unsigned char* zr = zq_sl + (size_t)(row0 + r) * 384 + col0;
            zr[0] = (unsigned char)(q & 0xFFu);
            zr[16] = (unsigned char)((q >> 8) & 0xFFu);
            unsigned int w = pk8x2(v0 * pw0, v1 * pw1);
            unsigned char* wr = zqw_sl + (size_t)(row0 + r) * 384 + col0;
            wr[0] = (unsigned char)(w & 0xFFu);
            wr[16] = (unsigned char)((w >> 8) & 0xFFu);
        }
    }
}

// ---------- loss: fp8 MFMA diagonal dot; 16 pairs per wave; partial per block ----------
__global__ __launch_bounds__(256) void loss_mfma_kernel(
    const unsigned char* __restrict__ zq, const unsigned char* __restrict__ zqw,
    const int* __restrict__ pos, const int* __restrict__ neg,
    const float* __restrict__ pb, float* __restrict__ partialOut,
    int p, float inv_total) {
    __shared__ float red[4];
    int lane = threadIdx.x & 63;
    int wv = threadIdx.x >> 6;
    int pairBase = (blockIdx.x * 4 + wv) * 16;
    float term = 0.f;
    if (pairBase < 2 * p) {
        int m = lane & 15;
        int kg = lane >> 4;
        int pi = pairBase + m;
        int pic = (pi < 2 * p) ? pi : (2 * p - 1);
        bool isneg = (pic >= p);
        const int* pr = isneg ? neg : pos;
        int idx = isneg ? (pic - p) : pic;
        int a = pr[idx];
        int b = pr[p + idx];
        const long* pa = reinterpret_cast<const long*>(zq + (size_t)a * 384) + kg;
        const long* pbw = reinterpret_cast<const long*>(zqw + (size_t)b * 384) + kg;
        long av[12], bv[12];
#pragma unroll
        for (int s = 0; s < 12; ++s) av[s] = pa[s * 4];
#pragma unroll
        for (int s = 0; s < 12; ++s) bv[s] = pbw[s * 4];
        f32x4 acc = {0.f, 0.f, 0.f, 0.f};
#pragma unroll
        for (int s = 0; s < 12; ++s) {
            acc = __builtin_amdgcn_mfma_f32_16x16x32_fp8_fp8(av[s], bv[s], acc, 0, 0, 0);
        }
        bool isdiag = (lane >> 4) == ((lane & 15) >> 2);
        int r2 = lane & 3;
        float v = (r2 == 0) ? acc[0] : (r2 == 1) ? acc[1] : (r2 == 2) ? acc[2] : acc[3];
        if (isdiag && pi < 2 * p) {
            float logit = v * 0.125f + pb[0];
            float t = isneg ? logit : -logit;
            term = (fmaxf(t, 0.f) + log1pf(expf(-fabsf(t)))) * inv_total;
        }
    }
#pragma unroll
    for (int off = 1; off < 64; off <<= 1) term += __shfl_xor(term, off);
    if (lane == 0) red[wv] = term;
    __syncthreads();
    if (threadIdx.x == 0) partialOut[blockIdx.x] = red[0] + red[1] + red[2] + red[3];
}

__global__ __launch_bounds__(256) void loss_reduce_kernel(
    const float* __restrict__ partial, float* __restrict__ out, int m) {
    __shared__ float s[256];
    float a = 0.f;
    for (int i = threadIdx.x; i < m; i += 256) a += partial[i];
    s[threadIdx.x] = a;
    __syncthreads();
    for (int off = 128; off > 0; off >>= 1) {
        if (threadIdx.x < off) s[threadIdx.x] += s[threadIdx.x + off];
        __syncthreads();
    }
    if (threadIdx.x == 0) out[0] = s[0];
}

extern "C" void kernel_launch(void* const* d_in, const int* in_sizes, int n_in,
                              void* d_out, int out_size, void* d_ws, size_t ws_size,
                              hipStream_t stream) {
    const float* x      = (const float*)d_in[0];
    const int*   ei     = (const int*)d_in[1];
    const int*   pos    = (const int*)d_in[2];
    const int*   neg    = (const int*)d_in[3];
    const float* gcn_w  = (const float*)d_in[4];
    const float* gcn_b  = (const float*)d_in[5];
    const float* pred_w = (const float*)d_in[6];
    const float* pred_b = (const float*)d_in[7];
    float* out = (float*)d_out;

    const int n = in_sizes[0] / DD;     // 50000
    const int e = in_sizes[1] / 2;      // 640000
    const int p = in_sizes[2] / 2;      // 100000
    const int nb = (n + 255) / 256;

    char* ws = (char*)d_ws;
    size_t off = 0;
    auto alloc = [&](size_t bytes) {
        void* ptr = ws + off;
        off += (bytes + 255) & ~(size_t)255;
        return ptr;
    };
    float* dinv      = (float*)alloc((size_t)n * 4);
    int*   counts    = (int*)alloc((size_t)n * 4);
    int*   rowptr    = (int*)alloc((size_t)(n + 1) * 4);
    int*   cursor    = (int*)alloc((size_t)n * 4);
    int*   partial   = (int*)alloc(256 * 4);
    int*   partial2  = (int*)alloc(256 * 4);
    float* lossPart  = (float*)alloc((size_t)4096 * 4);
    ushort* csr_src  = (ushort*)alloc((size_t)e * 2);
    ushort* wfrag    = (ushort*)alloc((size_t)3 * 2048 * 8 * 2);
    ushort* xh   = (ushort*)alloc((size_t)n * 128 * 2);
    ushort* aggh = (ushort*)alloc((size_t)n * 128 * 2);
    unsigned char* zq  = (unsigned char*)alloc((size_t)n * 384);
    unsigned char* zqw = (unsigned char*)alloc((size_t)n * 384);
    (void)ws_size;

    hipMemsetAsync(counts, 0, (size_t)n * 4, stream);

    count_kernel<<<(e + 255) / 256, 256, 0, stream>>>(counts, ei + e, e);
    dinv_kernel<<<nb, 256, 0, stream>>>(dinv, counts, n);
    scan_blocks<<<nb, 256, 0, stream>>>(counts, rowptr, partial, n);
    scan_partials<<<1, 256, 0, stream>>>(partial, partial2, nb);
    add_offsets<<<nb, 256, 0, stream>>>(rowptr, cursor, partial2, n, e);
    fill_kernel<<<(e + 255) / 256, 256, 0, stream>>>(ei, cursor, csr_src, e);

    size_t m8 = (size_t)n * 128 / 8;
    cvt_kernel<<<(int)((m8 + 255) / 256), 256, 0, stream>>>(x, xh, m8);
    wpack_kernel<<<24, 256, 0, stream>>>(gcn_w, wfrag);

    const int ntiles = n / 16;
    const int aggBlocks = (n * 64 + 255) / 256;
    for (int l = 0; l < 3; ++l) {
        if (l == 0) {
            aggregate_bf16_kernel<<<aggBlocks, 256, 0, stream>>>(
                xh, rowptr, csr_src, dinv, aggh, n);
        } else {
            aggregate_fp8_kernel<<<aggBlocks, 256, 0, stream>>>(
                zq + (size_t)(l - 1) * 128, rowptr, csr_src, dinv, aggh, n);
        }
        gemm_mfma_kernel<<<ntiles, 256, 0, stream>>>(
            aggh, wfrag + (size_t)l * 2048 * 8,
            gcn_b + (size_t)l * 128, pred_w + (size_t)l * 128,
            zq + (size_t)l * 128, zqw + (size_t)l * 128, ntiles);
    }

    float inv_total = 1.0f / (2.0f * (float)p);
    int lossBlocks = (2 * p + 63) / 64;  // 3125
    loss_mfma_kernel<<<lossBlocks, 256, 0, stream>>>(
        zq, zqw, pos, neg, pred_b, lossPart, p, inv_total);
    loss_reduce_kernel<<<1, 256, 0, stream>>>(lossPart, out, lossBlocks);
}

// Round 16
// 259.218 us; speedup vs baseline: 2.0075x; 1.0358x over previous
//
#include <hip/hip_runtime.h>
#include <hip/hip_bf16.h>

#define DD 128

typedef __attribute__((ext_vector_type(8))) short short8;
typedef __attribute__((ext_vector_type(4))) float f32x4;
typedef __attribute__((ext_vector_type(2))) float f32x2;

static __device__ __forceinline__ int gtid() {
    return blockIdx.x * blockDim.x + threadIdx.x;
}

static __device__ __forceinline__ ushort f2bfu(float f) {
    __hip_bfloat16 h = __float2bfloat16(f);
    return *reinterpret_cast<ushort*>(&h);
}

// ---- fp8 e4m3fn encode/decode (manual fallback, RNE, subnormal-correct) ----
static __device__ __forceinline__ unsigned int fp8e(float f) {
    unsigned int s = (__float_as_uint(f) >> 31) << 7;
    float a = fabsf(f);
    if (a < 0.015625f) return s | (unsigned int)rintf(a * 512.0f);
    unsigned int u = __float_as_uint(a);
    u += 0x0007FFFFu + ((u >> 20) & 1u);
    unsigned int e8 = (u >> 23) - 120u;
    unsigned int m = (u >> 20) & 7u;
    if (e8 > 15u || (e8 == 15u && m == 7u)) return s | 0x7Eu;
    return s | (e8 << 3) | m;
}

static __device__ __forceinline__ float fp8d(unsigned int b) {
    unsigned int t = b & 0x7Fu;
    float v = (t >= 8u) ? __uint_as_float((t << 20) + 0x3C000000u)
                        : (float)t * 0.001953125f;
    return (b & 0x80u) ? -v : v;
}

static __device__ __forceinline__ unsigned int pk8x2(float a, float b) {
#if __has_builtin(__builtin_amdgcn_cvt_pk_fp8_f32)
    return (unsigned int)__builtin_amdgcn_cvt_pk_fp8_f32(a, b, 0, false);
#else
    return fp8e(a) | (fp8e(b) << 8);
#endif
}

static __device__ __forceinline__ unsigned int pk8x4(float a, float b, float c, float d) {
#if __has_builtin(__builtin_amdgcn_cvt_pk_fp8_f32)
    int v = __builtin_amdgcn_cvt_pk_fp8_f32(a, b, 0, false);
    v = __builtin_amdgcn_cvt_pk_fp8_f32(c, d, v, true);
    return (unsigned int)v;
#else
    return fp8e(a) | (fp8e(b) << 8) | (fp8e(c) << 16) | (fp8e(d) << 24);
#endif
}

static __device__ __forceinline__ void fp8x4_dec(unsigned int u, float* f) {
#if __has_builtin(__builtin_amdgcn_cvt_pk_f32_fp8)
    f32x2 lo = __builtin_amdgcn_cvt_pk_f32_fp8((int)u, false);
    f32x2 hi = __builtin_amdgcn_cvt_pk_f32_fp8((int)u, true);
    f[0] = lo[0]; f[1] = lo[1]; f[2] = hi[0]; f[3] = hi[1];
#else
    f[0] = fp8d(u & 0xFFu);
    f[1] = fp8d((u >> 8) & 0xFFu);
    f[2] = fp8d((u >> 16) & 0xFFu);
    f[3] = fp8d((u >> 24) & 0xFFu);
#endif
}

// ---------- degree / CSR build (per-row cursors; ushort src entries) ----------

__global__ void count_kernel(int* __restrict__ counts, const int* __restrict__ dst, int e) {
    int i = gtid();
    if (i < e) atomicAdd(&counts[dst[i]], 1);
}

__global__ void dinv_kernel(float* __restrict__ dinv, const int* __restrict__ counts, int n) {
    int i = gtid();
    if (i < n) dinv[i] = rsqrtf(1.0f + (float)counts[i]);
}

__global__ __launch_bounds__(256) void scan_blocks(const int* __restrict__ counts,
                                                   int* __restrict__ rowptr,
                                                   int* __restrict__ partial, int n) {
    __shared__ int s[256];
    int i = blockIdx.x * 256 + threadIdx.x;
    int v = (i < n) ? counts[i] : 0;
    s[threadIdx.x] = v;
    __syncthreads();
    for (int off = 1; off < 256; off <<= 1) {
        int t = (threadIdx.x >= off) ? s[threadIdx.x - off] : 0;
        __syncthreads();
        s[threadIdx.x] += t;
        __syncthreads();
    }
    if (i < n) rowptr[i] = s[threadIdx.x] - v;
    if (threadIdx.x == 255) partial[blockIdx.x] = s[255];
}

__global__ __launch_bounds__(256) void scan_partials(int* __restrict__ partial,
                                                     int* __restrict__ partial2, int nb) {
    __shared__ int s[256];
    int v = (threadIdx.x < nb) ? partial[threadIdx.x] : 0;
    s[threadIdx.x] = v;
    __syncthreads();
    for (int off = 1; off < 256; off <<= 1) {
        int t = (threadIdx.x >= off) ? s[threadIdx.x - off] : 0;
        __syncthreads();
        s[threadIdx.x] += t;
        __syncthreads();
    }
    partial2[threadIdx.x] = s[threadIdx.x] - v;
}

__global__ __launch_bounds__(256) void add_offsets(int* __restrict__ rowptr,
                                                   int* __restrict__ cursor,
                                                   const int* __restrict__ partial2,
                                                   int n, int e) {
    int i = blockIdx.x * 256 + threadIdx.x;
    if (i < n) {
        int r = rowptr[i] + partial2[blockIdx.x];
        rowptr[i] = r;
        cursor[i] = r;
        if (i == n - 1) rowptr[n] = e;
    }
}

// ushort src entries: halves scattered-write footprint (n < 65536)
__global__ void fill_kernel(const int* __restrict__ ei, int* __restrict__ cursor,
                            ushort* __restrict__ csr_src, int e) {
    int i = gtid();
    if (i >= e) return;
    int s = ei[i];
    int d = ei[e + i];
    int pos = atomicAdd(&cursor[d], 1);
    csr_src[pos] = (ushort)s;
}

// ---------- x -> fp8 (vectorized: 8 elems/thread) ----------
__global__ void cvt_kernel(const float* __restrict__ x, unsigned char* __restrict__ xq, size_t m8) {
    size_t i = (size_t)blockIdx.x * blockDim.x + threadIdx.x;
    if (i >= m8) return;
    const float4* xp = reinterpret_cast<const float4*>(x + i * 8);
    float4 a = xp[0], b = xp[1];
    uint2 q;
    q.x = pk8x4(a.x, a.y, a.z, a.w);
    q.y = pk8x4(b.x, b.y, b.z, b.w);
    *reinterpret_cast<uint2*>(xq + i * 8) = q;
}

// ---------- W -> bf16 MFMA B-fragment order ----------
__global__ __launch_bounds__(256) void wpack_kernel(const float* __restrict__ gcn_w,
                                                    ushort* __restrict__ wfrag) {
    int tid = blockIdx.x * 256 + threadIdx.x;
    if (tid >= 3 * 4 * 8 * 64) return;
    int lane = tid & 63;
    int c = (tid >> 6) & 7;
    int s = (tid >> 9) & 3;
    int l = tid >> 11;
    const float* W = gcn_w + (size_t)l * 128 * 128;
    int col = c * 16 + (lane & 15);
    int k0 = s * 32 + (lane >> 4) * 8;
    ushort u[8];
#pragma unroll
    for (int j = 0; j < 8; ++j) {
        u[j] = f2bfu(W[(size_t)(k0 + j) * 128 + col]);
    }
    *reinterpret_cast<uint4*>(wfrag + (size_t)tid * 8) = *reinterpret_cast<const uint4*>(u);
}

// ---------- aggregate (fp8 source, parametric row stride): aggh = Ah ----------
// 8 edge slots (g=lane>>3) x 8 chunks (c=lane&7, 16 feats each)
__global__ __launch_bounds__(256) void aggregate_fp8_kernel(
    const unsigned char* __restrict__ srcq, int srcStride, const int* __restrict__ rowptr,
    const ushort* __restrict__ csr_src, const float* __restrict__ dinv,
    ushort* __restrict__ aggh, int n) {
    int gid = gtid();
    int row = gid >> 6;
    if (row >= n) return;
    int lane = threadIdx.x & 63;
    int g = lane >> 3;   // edge slot 0..7
    int c = lane & 7;    // feature chunk (16 feats)
    int j0 = rowptr[row], j1 = rowptr[row + 1];
    float dr = dinv[row];
    float acc[16];
#pragma unroll
    for (int k = 0; k < 16; ++k) acc[k] = 0.f;
    for (int j = j0 + g; j < j1; j += 8) {
        int s = (int)csr_src[j];
        float cf = dinv[s] * dr;
        uint4 v = *reinterpret_cast<const uint4*>(srcq + (size_t)s * srcStride + c * 16);
        float f[16];
        fp8x4_dec(v.x, f);
        fp8x4_dec(v.y, f + 4);
        fp8x4_dec(v.z, f + 8);
        fp8x4_dec(v.w, f + 12);
#pragma unroll
        for (int k = 0; k < 16; ++k) acc[k] = fmaf(cf, f[k], acc[k]);
    }
#pragma unroll
    for (int k = 0; k < 16; ++k) {
        acc[k] += __shfl_xor(acc[k], 8);
        acc[k] += __shfl_xor(acc[k], 16);
        acc[k] += __shfl_xor(acc[k], 32);
    }
    float d2 = dr * dr;
    uint4 sv = *reinterpret_cast<const uint4*>(srcq + (size_t)row * srcStride + c * 16);
    float sf[16];
    fp8x4_dec(sv.x, sf);
    fp8x4_dec(sv.y, sf + 4);
    fp8x4_dec(sv.z, sf + 8);
    fp8x4_dec(sv.w, sf + 12);
#pragma unroll
    for (int k = 0; k < 16; ++k) acc[k] = fmaf(d2, sf[k], acc[k]);
    if (g == 0) {
        unsigned int pk[8];
#pragma unroll
        for (int q = 0; q < 8; ++q) {
            pk[q] = (unsigned int)f2bfu(acc[2 * q]) | ((unsigned int)f2bfu(acc[2 * q + 1]) << 16);
        }
        ushort* ap = aggh + (size_t)row * 128 + c * 16;
        *reinterpret_cast<uint4*>(ap) = *reinterpret_cast<const uint4*>(pk);
        *reinterpret_cast<uint4*>(ap + 8) = *reinterpret_cast<const uint4*>(pk + 4);
    }
}

// ---------- MFMA GEMM: aggh @ W + bias -> relu -> zq (fp8) + zqw (fp8*pw*8) ----------
__global__ __launch_bounds__(256) void gemm_mfma_kernel(
    const ushort* __restrict__ aggh, const ushort* __restrict__ wfrag,
    const float* __restrict__ bias, const float* __restrict__ pwsl,
    unsigned char* __restrict__ zq_sl, unsigned char* __restrict__ zqw_sl, int ntiles) {
    int lane = threadIdx.x & 63;
    int wv = threadIdx.x >> 6;
    short8 b0[4], b1[4];
    int c0 = wv * 2;
#pragma unroll
    for (int s = 0; s < 4; ++s) {
        b0[s] = *reinterpret_cast<const short8*>(wfrag + ((size_t)(s * 8 + c0) * 64 + lane) * 8);
        b1[s] = *reinterpret_cast<const short8*>(wfrag + ((size_t)(s * 8 + c0 + 1) * 64 + lane) * 8);
    }
    int rlo = lane & 15;
    int kg = lane >> 4;
    int col0 = wv * 32 + rlo;
    int col1 = col0 + 16;
    float bias0 = bias[col0], bias1 = bias[col1];
    float pw0 = pwsl[col0] * 8.0f, pw1 = pwsl[col1] * 8.0f;
    for (int rt = blockIdx.x; rt < ntiles; rt += gridDim.x) {
        const ushort* ap = aggh + (size_t)(rt * 16 + rlo) * 128 + kg * 8;
        short8 a0 = *reinterpret_cast<const short8*>(ap);
        short8 a1 = *reinterpret_cast<const short8*>(ap + 32);
        short8 a2 = *reinterpret_cast<const short8*>(ap + 64);
        short8 a3 = *reinterpret_cast<const short8*>(ap + 96);
        f32x4 acc0 = {0.f, 0.f, 0.f, 0.f};
        f32x4 acc1 = {0.f, 0.f, 0.f, 0.f};
        acc0 = __builtin_amdgcn_mfma_f32_16x16x32_bf16(a0, b0[0], acc0, 0, 0, 0);
        acc1 = __builtin_amdgcn_mfma_f32_16x16x32_bf16(a0, b1[0], acc1, 0, 0, 0);
        acc0 = __builtin_amdgcn_mfma_f32_16x16x32_bf16(a1, b0[1], acc0, 0, 0, 0);
        acc1 = __builtin_amdgcn_mfma_f32_16x16x32_bf16(a1, b1[1], acc1, 0, 0, 0);
        acc0 = __builtin_amdgcn_mfma_f32_16x16x32_bf16(a2, b0[2], acc0, 0, 0, 0);
        acc1 = __builtin_amdgcn_mfma_f32_16x16x32_bf16(a2, b1[2], acc1, 0, 0, 0);
        acc0 = __builtin_amdgcn_mfma_f32_16x16x32_bf16(a3, b0[3], acc0, 0, 0, 0);
        acc1 = __builtin_amdgcn_mfma_f32_16x16x32_bf16(a3, b1[3], acc1, 0, 0, 0);
        int row0 = rt * 16 + kg * 4;
#pragma unroll
        for (int r = 0; r < 4; ++r) {
            float v0 = fmaxf(acc0[r] + bias0, 0.f);
            float v1 = fmaxf(acc1[r] + bias1, 0.f);
            unsigned int q = pk8x2(v0, v1);
            unsigned char* zr = zq_sl + (size_t)(row0 + r) * 384 + col0;
            zr[0] = (unsigned char)(q & 0xFFu);
            zr[16] = (unsigned char)((q >> 8) & 0xFFu);
            unsigned int w = pk8x2(v0 * pw0, v1 * pw1);
            unsigned char* wr = zqw_sl + (size_t)(row0 + r) * 384 + col0;
            wr[0] = (unsigned char)(w & 0xFFu);
            wr[16] = (unsigned char)((w >> 8) & 0xFFu);
        }
    }
}

// ---------- loss: fp8 MFMA diagonal dot; 16 pairs per wave; partial per block ----------
__global__ __launch_bounds__(256) void loss_mfma_kernel(
    const unsigned char* __restrict__ zq, const unsigned char* __restrict__ zqw,
    const int* __restrict__ pos, const int* __restrict__ neg,
    const float* __restrict__ pb, float* __restrict__ partialOut,
    int p, float inv_total) {
    __shared__ float red[4];
    int lane = threadIdx.x & 63;
    int wv = threadIdx.x >> 6;
    int pairBase = (blockIdx.x * 4 + wv) * 16;
    float term = 0.f;
    if (pairBase < 2 * p) {
        int m = lane & 15;
        int kg = lane >> 4;
        int pi = pairBase + m;
        int pic = (pi < 2 * p) ? pi : (2 * p - 1);
        bool isneg = (pic >= p);
        const int* pr = isneg ? neg : pos;
        int idx = isneg ? (pic - p) : pic;
        int a = pr[idx];
        int b = pr[p + idx];
        const long* pa = reinterpret_cast<const long*>(zq + (size_t)a * 384) + kg;
        const long* pbw = reinterpret_cast<const long*>(zqw + (size_t)b * 384) + kg;
        long av[12], bv[12];
#pragma unroll
        for (int s = 0; s < 12; ++s) av[s] = pa[s * 4];
#pragma unroll
        for (int s = 0; s < 12; ++s) bv[s] = pbw[s * 4];
        f32x4 acc = {0.f, 0.f, 0.f, 0.f};
#pragma unroll
        for (int s = 0; s < 12; ++s) {
            acc = __builtin_amdgcn_mfma_f32_16x16x32_fp8_fp8(av[s], bv[s], acc, 0, 0, 0);
        }
        bool isdiag = (lane >> 4) == ((lane & 15) >> 2);
        int r2 = lane & 3;
        float v = (r2 == 0) ? acc[0] : (r2 == 1) ? acc[1] : (r2 == 2) ? acc[2] : acc[3];
        if (isdiag && pi < 2 * p) {
            float logit = v * 0.125f + pb[0];
            float t = isneg ? logit : -logit;
            term = (fmaxf(t, 0.f) + log1pf(expf(-fabsf(t)))) * inv_total;
        }
    }
#pragma unroll
    for (int off = 1; off < 64; off <<= 1) term += __shfl_xor(term, off);
    if (lane == 0) red[wv] = term;
    __syncthreads();
    if (threadIdx.x == 0) partialOut[blockIdx.x] = red[0] + red[1] + red[2] + red[3];
}

__global__ __launch_bounds__(256) void loss_reduce_kernel(
    const float* __restrict__ partial, float* __restrict__ out, int m) {
    __shared__ float s[256];
    float a = 0.f;
    for (int i = threadIdx.x; i < m; i += 256) a += partial[i];
    s[threadIdx.x] = a;
    __syncthreads();
    for (int off = 128; off > 0; off >>= 1) {
        if (threadIdx.x < off) s[threadIdx.x] += s[threadIdx.x + off];
        __syncthreads();
    }
    if (threadIdx.x == 0) out[0] = s[0];
}

extern "C" void kernel_launch(void* const* d_in, const int* in_sizes, int n_in,
                              void* d_out, int out_size, void* d_ws, size_t ws_size,
                              hipStream_t stream) {
    const float* x      = (const float*)d_in[0];
    const int*   ei     = (const int*)d_in[1];
    const int*   pos    = (const int*)d_in[2];
    const int*   neg    = (const int*)d_in[3];
    const float* gcn_w  = (const float*)d_in[4];
    const float* gcn_b  = (const float*)d_in[5];
    const float* pred_w = (const float*)d_in[6];
    const float* pred_b = (const float*)d_in[7];
    float* out = (float*)d_out;

    const int n = in_sizes[0] / DD;     // 50000
    const int e = in_sizes[1] / 2;      // 640000
    const int p = in_sizes[2] / 2;      // 100000
    const int nb = (n + 255) / 256;

    char* ws = (char*)d_ws;
    size_t off = 0;
    auto alloc = [&](size_t bytes) {
        void* ptr = ws + off;
        off += (bytes + 255) & ~(size_t)255;
        return ptr;
    };
    float* dinv      = (float*)alloc((size_t)n * 4);
    int*   counts    = (int*)alloc((size_t)n * 4);
    int*   rowptr    = (int*)alloc((size_t)(n + 1) * 4);
    int*   cursor    = (int*)alloc((size_t)n * 4);
    int*   partial   = (int*)alloc(256 * 4);
    int*   partial2  = (int*)alloc(256 * 4);
    float* lossPart  = (float*)alloc((size_t)4096 * 4);
    ushort* csr_src  = (ushort*)alloc((size_t)e * 2);
    ushort* wfrag    = (ushort*)alloc((size_t)3 * 2048 * 8 * 2);
    unsigned char* xq = (unsigned char*)alloc((size_t)n * 128);
    ushort* aggh = (ushort*)alloc((size_t)n * 128 * 2);
    unsigned char* zq  = (unsigned char*)alloc((size_t)n * 384);
    unsigned char* zqw = (unsigned char*)alloc((size_t)n * 384);
    (void)ws_size;

    hipMemsetAsync(counts, 0, (size_t)n * 4, stream);

    count_kernel<<<(e + 255) / 256, 256, 0, stream>>>(counts, ei + e, e);
    dinv_kernel<<<nb, 256, 0, stream>>>(dinv, counts, n);
    scan_blocks<<<nb, 256, 0, stream>>>(counts, rowptr, partial, n);
    scan_partials<<<1, 256, 0, stream>>>(partial, partial2, nb);
    add_offsets<<<nb, 256, 0, stream>>>(rowptr, cursor, partial2, n, e);
    fill_kernel<<<(e + 255) / 256, 256, 0, stream>>>(ei, cursor, csr_src, e);

    size_t m8 = (size_t)n * 128 / 8;
    cvt_kernel<<<(int)((m8 + 255) / 256), 256, 0, stream>>>(x, xq, m8);
    wpack_kernel<<<24, 256, 0, stream>>>(gcn_w, wfrag);

    const int ntiles = n / 16;
    const int aggBlocks = (n * 64 + 255) / 256;
    for (int l = 0; l < 3; ++l) {
        const unsigned char* srcq = (l == 0) ? xq : (zq + (size_t)(l - 1) * 128);
        int srcStride = (l == 0) ? 128 : 384;
        aggregate_fp8_kernel<<<aggBlocks, 256, 0, stream>>>(
            srcq, srcStride, rowptr, csr_src, dinv, aggh, n);
        gemm_mfma_kernel<<<ntiles, 256, 0, stream>>>(
            aggh, wfrag + (size_t)l * 2048 * 8,
            gcn_b + (size_t)l * 128, pred_w + (size_t)l * 128,
            zq + (size_t)l * 128, zqw + (size_t)l * 128, ntiles);
    }

    float inv_total = 1.0f / (2.0f * (float)p);
    int lossBlocks = (2 * p + 63) / 64;  // 3125
    loss_mfma_kernel<<<lossBlocks, 256, 0, stream>>>(
        zq, zqw, pos, neg, pred_b, lossPart, p, inv_total);
    loss_reduce_kernel<<<1, 256, 0, stream>>>(lossPart, out, lossBlocks);
}

// Round 17
// 255.589 us; speedup vs baseline: 2.0360x; 1.0142x over previous
//
#include <hip/hip_runtime.h>
#include <hip/hip_bf16.h>

#define DD 128

typedef __attribute__((ext_vector_type(8))) short short8;
typedef __attribute__((ext_vector_type(4))) float f32x4;
typedef __attribute__((ext_vector_type(2))) float f32x2;

static __device__ __forceinline__ int gtid() {
    return blockIdx.x * blockDim.x + threadIdx.x;
}

static __device__ __forceinline__ ushort f2bfu(float f) {
    __hip_bfloat16 h = __float2bfloat16(f);
    return *reinterpret_cast<ushort*>(&h);
}

// ---- fp8 e4m3fn encode/decode (manual fallback, RNE, subnormal-correct) ----
static __device__ __forceinline__ unsigned int fp8e(float f) {
    unsigned int s = (__float_as_uint(f) >> 31) << 7;
    float a = fabsf(f);
    if (a < 0.015625f) return s | (unsigned int)rintf(a * 512.0f);
    unsigned int u = __float_as_uint(a);
    u += 0x0007FFFFu + ((u >> 20) & 1u);
    unsigned int e8 = (u >> 23) - 120u;
    unsigned int m = (u >> 20) & 7u;
    if (e8 > 15u || (e8 == 15u && m == 7u)) return s | 0x7Eu;
    return s | (e8 << 3) | m;
}

static __device__ __forceinline__ float fp8d(unsigned int b) {
    unsigned int t = b & 0x7Fu;
    float v = (t >= 8u) ? __uint_as_float((t << 20) + 0x3C000000u)
                        : (float)t * 0.001953125f;
    return (b & 0x80u) ? -v : v;
}

static __device__ __forceinline__ unsigned int pk8x2(float a, float b) {
#if __has_builtin(__builtin_amdgcn_cvt_pk_fp8_f32)
    return (unsigned int)__builtin_amdgcn_cvt_pk_fp8_f32(a, b, 0, false);
#else
    return fp8e(a) | (fp8e(b) << 8);
#endif
}

static __device__ __forceinline__ unsigned int pk8x4(float a, float b, float c, float d) {
#if __has_builtin(__builtin_amdgcn_cvt_pk_fp8_f32)
    int v = __builtin_amdgcn_cvt_pk_fp8_f32(a, b, 0, false);
    v = __builtin_amdgcn_cvt_pk_fp8_f32(c, d, v, true);
    return (unsigned int)v;
#else
    return fp8e(a) | (fp8e(b) << 8) | (fp8e(c) << 16) | (fp8e(d) << 24);
#endif
}

static __device__ __forceinline__ void fp8x4_dec(unsigned int u, float* f) {
#if __has_builtin(__builtin_amdgcn_cvt_pk_f32_fp8)
    f32x2 lo = __builtin_amdgcn_cvt_pk_f32_fp8((int)u, false);
    f32x2 hi = __builtin_amdgcn_cvt_pk_f32_fp8((int)u, true);
    f[0] = lo[0]; f[1] = lo[1]; f[2] = hi[0]; f[3] = hi[1];
#else
    f[0] = fp8d(u & 0xFFu);
    f[1] = fp8d((u >> 8) & 0xFFu);
    f[2] = fp8d((u >> 16) & 0xFFu);
    f[3] = fp8d((u >> 24) & 0xFFu);
#endif
}

// ---------- degree / CSR build (per-row cursors; ushort src entries) ----------

__global__ void count_kernel(int* __restrict__ counts, const int* __restrict__ dst, int e) {
    int i = gtid();
    if (i < e) atomicAdd(&counts[dst[i]], 1);
}

// scan + dinv fused (dinv[i] = rsqrt(1+counts[i]))
__global__ __launch_bounds__(256) void scan_blocks(const int* __restrict__ counts,
                                                   int* __restrict__ rowptr,
                                                   int* __restrict__ partial,
                                                   float* __restrict__ dinv, int n) {
    __shared__ int s[256];
    int i = blockIdx.x * 256 + threadIdx.x;
    int v = (i < n) ? counts[i] : 0;
    if (i < n) dinv[i] = rsqrtf(1.0f + (float)v);
    s[threadIdx.x] = v;
    __syncthreads();
    for (int off = 1; off < 256; off <<= 1) {
        int t = (threadIdx.x >= off) ? s[threadIdx.x - off] : 0;
        __syncthreads();
        s[threadIdx.x] += t;
        __syncthreads();
    }
    if (i < n) rowptr[i] = s[threadIdx.x] - v;
    if (threadIdx.x == 255) partial[blockIdx.x] = s[255];
}

__global__ __launch_bounds__(256) void scan_partials(int* __restrict__ partial,
                                                     int* __restrict__ partial2, int nb) {
    __shared__ int s[256];
    int v = (threadIdx.x < nb) ? partial[threadIdx.x] : 0;
    s[threadIdx.x] = v;
    __syncthreads();
    for (int off = 1; off < 256; off <<= 1) {
        int t = (threadIdx.x >= off) ? s[threadIdx.x - off] : 0;
        __syncthreads();
        s[threadIdx.x] += t;
        __syncthreads();
    }
    partial2[threadIdx.x] = s[threadIdx.x] - v;
}

__global__ __launch_bounds__(256) void add_offsets(int* __restrict__ rowptr,
                                                   int* __restrict__ cursor,
                                                   const int* __restrict__ partial2,
                                                   int n, int e) {
    int i = blockIdx.x * 256 + threadIdx.x;
    if (i < n) {
        int r = rowptr[i] + partial2[blockIdx.x];
        rowptr[i] = r;
        cursor[i] = r;
        if (i == n - 1) rowptr[n] = e;
    }
}

// dst-windowed scatter: partition = blockIdx&7 (aligns with round-robin XCD
// dispatch); each partition's writes confined to a ~160KB csr_src window.
__global__ __launch_bounds__(256) void fill_kernel(
    const int* __restrict__ ei, int* __restrict__ cursor,
    ushort* __restrict__ csr_src, int e, int n, int blocksPerPart) {
    int part = blockIdx.x & 7;
    int blk = blockIdx.x >> 3;
    int lo = (int)(((long)n * part) >> 3);
    int hi = (int)(((long)n * (part + 1)) >> 3);
    int stride = blocksPerPart * 256;
    for (int i = blk * 256 + threadIdx.x; i < e; i += stride) {
        int d = ei[e + i];
        if (d < lo || d >= hi) continue;
        int s = ei[i];
        int pos = atomicAdd(&cursor[d], 1);
        csr_src[pos] = (ushort)s;
    }
}

// ---------- x -> fp8 (vectorized: 8 elems/thread) ----------
__global__ void cvt_kernel(const float* __restrict__ x, unsigned char* __restrict__ xq, size_t m8) {
    size_t i = (size_t)blockIdx.x * blockDim.x + threadIdx.x;
    if (i >= m8) return;
    const float4* xp = reinterpret_cast<const float4*>(x + i * 8);
    float4 a = xp[0], b = xp[1];
    uint2 q;
    q.x = pk8x4(a.x, a.y, a.z, a.w);
    q.y = pk8x4(b.x, b.y, b.z, b.w);
    *reinterpret_cast<uint2*>(xq + i * 8) = q;
}

// ---------- W -> bf16 MFMA B-fragment order ----------
__global__ __launch_bounds__(256) void wpack_kernel(const float* __restrict__ gcn_w,
                                                    ushort* __restrict__ wfrag) {
    int tid = blockIdx.x * 256 + threadIdx.x;
    if (tid >= 3 * 4 * 8 * 64) return;
    int lane = tid & 63;
    int c = (tid >> 6) & 7;
    int s = (tid >> 9) & 3;
    int l = tid >> 11;
    const float* W = gcn_w + (size_t)l * 128 * 128;
    int col = c * 16 + (lane & 15);
    int k0 = s * 32 + (lane >> 4) * 8;
    ushort u[8];
#pragma unroll
    for (int j = 0; j < 8; ++j) {
        u[j] = f2bfu(W[(size_t)(k0 + j) * 128 + col]);
    }
    *reinterpret_cast<uint4*>(wfrag + (size_t)tid * 8) = *reinterpret_cast<const uint4*>(u);
}

// ---------- aggregate (fp8 source, parametric row stride): aggh = Ah ----------
__global__ __launch_bounds__(256) void aggregate_fp8_kernel(
    const unsigned char* __restrict__ srcq, int srcStride, const int* __restrict__ rowptr,
    const ushort* __restrict__ csr_src, const float* __restrict__ dinv,
    ushort* __restrict__ aggh, int n) {
    int gid = gtid();
    int row = gid >> 6;
    if (row >= n) return;
    int lane = threadIdx.x & 63;
    int g = lane >> 3;   // edge slot 0..7
    int c = lane & 7;    // feature chunk (16 feats)
    int j0 = rowptr[row], j1 = rowptr[row + 1];
    float dr = dinv[row];
    float acc[16];
#pragma unroll
    for (int k = 0; k < 16; ++k) acc[k] = 0.f;
    for (int j = j0 + g; j < j1; j += 8) {
        int s = (int)csr_src[j];
        float cf = dinv[s] * dr;
        uint4 v = *reinterpret_cast<const uint4*>(srcq + (size_t)s * srcStride + c * 16);
        float f[16];
        fp8x4_dec(v.x, f);
        fp8x4_dec(v.y, f + 4);
        fp8x4_dec(v.z, f + 8);
        fp8x4_dec(v.w, f + 12);
#pragma unroll
        for (int k = 0; k < 16; ++k) acc[k] = fmaf(cf, f[k], acc[k]);
    }
#pragma unroll
    for (int k = 0; k < 16; ++k) {
        acc[k] += __shfl_xor(acc[k], 8);
        acc[k] += __shfl_xor(acc[k], 16);
        acc[k] += __shfl_xor(acc[k], 32);
    }
    float d2 = dr * dr;
    uint4 sv = *reinterpret_cast<const uint4*>(srcq + (size_t)row * srcStride + c * 16);
    float sf[16];
    fp8x4_dec(sv.x, sf);
    fp8x4_dec(sv.y, sf + 4);
    fp8x4_dec(sv.z, sf + 8);
    fp8x4_dec(sv.w, sf + 12);
#pragma unroll
    for (int k = 0; k < 16; ++k) acc[k] = fmaf(d2, sf[k], acc[k]);
    if (g == 0) {
        unsigned int pk[8];
#pragma unroll
        for (int q = 0; q < 8; ++q) {
            pk[q] = (unsigned int)f2bfu(acc[2 * q]) | ((unsigned int)f2bfu(acc[2 * q + 1]) << 16);
        }
        ushort* ap = aggh + (size_t)row * 128 + c * 16;
        *reinterpret_cast<uint4*>(ap) = *reinterpret_cast<const uint4*>(pk);
        *reinterpret_cast<uint4*>(ap + 8) = *reinterpret_cast<const uint4*>(pk + 4);
    }
}

// ---------- MFMA GEMM: aggh @ W + bias -> relu -> zq (fp8) + zqw (fp8*pw*8) ----------
__global__ __launch_bounds__(256) void gemm_mfma_kernel(
    const ushort* __restrict__ aggh, const ushort* __restrict__ wfrag,
    const float* __restrict__ bias, const float* __restrict__ pwsl,
    unsigned char* __restrict__ zq_sl, unsigned char* __restrict__ zqw_sl, int ntiles) {
    int lane = threadIdx.x & 63;
    int wv = threadIdx.x >> 6;
    short8 b0[4], b1[4];
    int c0 = wv * 2;
#pragma unroll
    for (int s = 0; s < 4; ++s) {
        b0[s] = *reinterpret_cast<const short8*>(wfrag + ((size_t)(s * 8 + c0) * 64 + lane) * 8);
        b1[s] = *reinterpret_cast<const short8*>(wfrag + ((size_t)(s * 8 + c0 + 1) * 64 + lane) * 8);
    }
    int rlo = lane & 15;
    int kg = lane >> 4;
    int col0 = wv * 32 + rlo;
    int col1 = col0 + 16;
    float bias0 = bias[col0], bias1 = bias[col1];
    float pw0 = pwsl[col0] * 8.0f, pw1 = pwsl[col1] * 8.0f;
    for (int rt = blockIdx.x; rt < ntiles; rt += gridDim.x) {
        const ushort* ap = aggh + (size_t)(rt * 16 + rlo) * 128 + kg * 8;
        short8 a0 = *reinterpret_cast<const short8*>(ap);
        short8 a1 = *reinterpret_cast<const short8*>(ap + 32);
        short8 a2 = *reinterpret_cast<const short8*>(ap + 64);
        short8 a3 = *reinterpret_cast<const short8*>(ap + 96);
        f32x4 acc0 = {0.f, 0.f, 0.f, 0.f};
        f32x4 acc1 = {0.f, 0.f, 0.f, 0.f};
        acc0 = __builtin_amdgcn_mfma_f32_16x16x32_bf16(a0, b0[0], acc0, 0, 0, 0);
        acc1 = __builtin_amdgcn_mfma_f32_16x16x32_bf16(a0, b1[0], acc1, 0, 0, 0);
        acc0 = __builtin_amdgcn_mfma_f32_16x16x32_bf16(a1, b0[1], acc0, 0, 0, 0);
        acc1 = __builtin_amdgcn_mfma_f32_16x16x32_bf16(a1, b1[1], acc1, 0, 0, 0);
        acc0 = __builtin_amdgcn_mfma_f32_16x16x32_bf16(a2, b0[2], acc0, 0, 0, 0);
        acc1 = __builtin_amdgcn_mfma_f32_16x16x32_bf16(a2, b1[2], acc1, 0, 0, 0);
        acc0 = __builtin_amdgcn_mfma_f32_16x16x32_bf16(a3, b0[3], acc0, 0, 0, 0);
        acc1 = __builtin_amdgcn_mfma_f32_16x16x32_bf16(a3, b1[3], acc1, 0, 0, 0);
        int row0 = rt * 16 + kg * 4;
#pragma unroll
        for (int r = 0; r < 4; ++r) {
            float v0 = fmaxf(acc0[r] + bias0, 0.f);
            float v1 = fmaxf(acc1[r] + bias1, 0.f);
            unsigned int q = pk8x2(v0, v1);
            unsigned char* zr = zq_sl + (size_t)(row0 + r) * 384 + col0;
            zr[0] = (unsigned char)(q & 0xFFu);
            zr[16] = (unsigned char)((q >> 8) & 0xFFu);
            unsigned int w = pk8x2(v0 * pw0, v1 * pw1);
            unsigned char* wr = zqw_sl + (size_t)(row0 + r) * 384 + col0;
            wr[0] = (unsigned char)(w & 0xFFu);
            wr[16] = (unsigned char)((w >> 8) & 0xFFu);
        }
    }
}

// ---------- loss: fp8 MFMA diagonal dot; 16 pairs per wave; partial per block ----------
__global__ __launch_bounds__(256) void loss_mfma_kernel(
    const unsigned char* __restrict__ zq, const unsigned char* __restrict__ zqw,
    const int* __restrict__ pos, const int* __restrict__ neg,
    const float* __restrict__ pb, float* __restrict__ partialOut,
    int p, float inv_total) {
    __shared__ float red[4];
    int lane = threadIdx.x & 63;
    int wv = threadIdx.x >> 6;
    int pairBase = (blockIdx.x * 4 + wv) * 16;
    float term = 0.f;
    if (pairBase < 2 * p) {
        int m = lane & 15;
        int kg = lane >> 4;
        int pi = pairBase + m;
        int pic = (pi < 2 * p) ? pi : (2 * p - 1);
        bool isneg = (pic >= p);
        const int* pr = isneg ? neg : pos;
        int idx = isneg ? (pic - p) : pic;
        int a = pr[idx];
        int b = pr[p + idx];
        const long* pa = reinterpret_cast<const long*>(zq + (size_t)a * 384) + kg;
        const long* pbw = reinterpret_cast<const long*>(zqw + (size_t)b * 384) + kg;
        long av[12], bv[12];
#pragma unroll
        for (int s = 0; s < 12; ++s) av[s] = pa[s * 4];
#pragma unroll
        for (int s = 0; s < 12; ++s) bv[s] = pbw[s * 4];
        f32x4 acc = {0.f, 0.f, 0.f, 0.f};
#pragma unroll
        for (int s = 0; s < 12; ++s) {
            acc = __builtin_amdgcn_mfma_f32_16x16x32_fp8_fp8(av[s], bv[s], acc, 0, 0, 0);
        }
        bool isdiag = (lane >> 4) == ((lane & 15) >> 2);
        int r2 = lane & 3;
        float v = (r2 == 0) ? acc[0] : (r2 == 1) ? acc[1] : (r2 == 2) ? acc[2] : acc[3];
        if (isdiag && pi < 2 * p) {
            float logit = v * 0.125f + pb[0];
            float t = isneg ? logit : -logit;
            term = (fmaxf(t, 0.f) + log1pf(expf(-fabsf(t)))) * inv_total;
        }
    }
#pragma unroll
    for (int off = 1; off < 64; off <<= 1) term += __shfl_xor(term, off);
    if (lane == 0) red[wv] = term;
    __syncthreads();
    if (threadIdx.x == 0) partialOut[blockIdx.x] = red[0] + red[1] + red[2] + red[3];
}

__global__ __launch_bounds__(256) void loss_reduce_kernel(
    const float* __restrict__ partial, float* __restrict__ out, int m) {
    __shared__ float s[256];
    float a = 0.f;
    for (int i = threadIdx.x; i < m; i += 256) a += partial[i];
    s[threadIdx.x] = a;
    __syncthreads();
    for (int off = 128; off > 0; off >>= 1) {
        if (threadIdx.x < off) s[threadIdx.x] += s[threadIdx.x + off];
        __syncthreads();
    }
    if (threadIdx.x == 0) out[0] = s[0];
}

extern "C" void kernel_launch(void* const* d_in, const int* in_sizes, int n_in,
                              void* d_out, int out_size, void* d_ws, size_t ws_size,
                              hipStream_t stream) {
    const float* x      = (const float*)d_in[0];
    const int*   ei     = (const int*)d_in[1];
    const int*   pos    = (const int*)d_in[2];
    const int*   neg    = (const int*)d_in[3];
    const float* gcn_w  = (const float*)d_in[4];
    const float* gcn_b  = (const float*)d_in[5];
    const float* pred_w = (const float*)d_in[6];
    const float* pred_b = (const float*)d_in[7];
    float* out = (float*)d_out;

    const int n = in_sizes[0] / DD;     // 50000
    const int e = in_sizes[1] / 2;      // 640000
    const int p = in_sizes[2] / 2;      // 100000
    const int nb = (n + 255) / 256;

    char* ws = (char*)d_ws;
    size_t off = 0;
    auto alloc = [&](size_t bytes) {
        void* ptr = ws + off;
        off += (bytes + 255) & ~(size_t)255;
        return ptr;
    };
    float* dinv      = (float*)alloc((size_t)n * 4);
    int*   counts    = (int*)alloc((size_t)n * 4);
    int*   rowptr    = (int*)alloc((size_t)(n + 1) * 4);
    int*   cursor    = (int*)alloc((size_t)n * 4);
    int*   partial   = (int*)alloc(256 * 4);
    int*   partial2  = (int*)alloc(256 * 4);
    float* lossPart  = (float*)alloc((size_t)4096 * 4);
    ushort* csr_src  = (ushort*)alloc((size_t)e * 2);
    ushort* wfrag    = (ushort*)alloc((size_t)3 * 2048 * 8 * 2);
    unsigned char* xq = (unsigned char*)alloc((size_t)n * 128);
    ushort* aggh = (ushort*)alloc((size_t)n * 128 * 2);
    unsigned char* zq  = (unsigned char*)alloc((size_t)n * 384);
    unsigned char* zqw = (unsigned char*)alloc((size_t)n * 384);
    (void)ws_size;

    hipMemsetAsync(counts, 0, (size_t)n * 4, stream);

    count_kernel<<<(e + 255) / 256, 256, 0, stream>>>(counts, ei + e, e);
    scan_blocks<<<nb, 256, 0, stream>>>(counts, rowptr, partial, dinv, n);
    scan_partials<<<1, 256, 0, stream>>>(partial, partial2, nb);
    add_offsets<<<nb, 256, 0, stream>>>(rowptr, cursor, partial2, n, e);
    int blocksPerPart = (e + 255) / 256 / 2;  // each partition strides over all edges
    fill_kernel<<<blocksPerPart * 8, 256, 0, stream>>>(ei, cursor, csr_src, e, n, blocksPerPart);

    size_t m8 = (size_t)n * 128 / 8;
    cvt_kernel<<<(int)((m8 + 255) / 256), 256, 0, stream>>>(x, xq, m8);
    wpack_kernel<<<24, 256, 0, stream>>>(gcn_w, wfrag);

    const int ntiles = n / 16;
    const int aggBlocks = (n * 64 + 255) / 256;
    for (int l = 0; l < 3; ++l) {
        const unsigned char* srcq = (l == 0) ? xq : (zq + (size_t)(l - 1) * 128);
        int srcStride = (l == 0) ? 128 : 384;
        aggregate_fp8_kernel<<<aggBlocks, 256, 0, stream>>>(
            srcq, srcStride, rowptr, csr_src, dinv, aggh, n);
        gemm_mfma_kernel<<<ntiles, 256, 0, stream>>>(
            aggh, wfrag + (size_t)l * 2048 * 8,
            gcn_b + (size_t)l * 128, pred_w + (size_t)l * 128,
            zq + (size_t)l * 128, zqw + (size_t)l * 128, ntiles);
    }

    float inv_total = 1.0f / (2.0f * (float)p);
    int lossBlocks = (2 * p + 63) / 64;  // 3125
    loss_mfma_kernel<<<lossBlocks, 256, 0, stream>>>(
        zq, zqw, pos, neg, pred_b, lossPart, p, inv_total);
    loss_reduce_kernel<<<1, 256, 0, stream>>>(lossPart, out, lossBlocks);
}